// Round 2
// baseline (445.079 us; speedup 1.0000x reference)
//
#include <hip/hip_runtime.h>
#include <cstddef>
#include <cstdint>

// LinearAttention — bf16 MFMA, global_load_lds staging, XOR-swizzled LDS.
// B=4 L=4096 D=1024 H=16 d=64 M=128 (2M=256).
// Pipeline: K0 fused convert (x+weights+projT, 1 launch) -> K1 fused QKV GEMM
// -> K2 fourier(k)+kv outer (private partials) -> K2.5 reduce+transpose
// -> K3 fourier(q)+attn (kvT read direct from L2, barrier-light) -> K4 out GEMM.
//
// ws layout (bytes):
//   qb     @ 0          33.55MB  bf16 [16384][1024]
//   kb     @ 33554432   33.55MB  bf16 [16384][1024]   (reused as attnb)
//   vT     @ 67108864   33.55MB  bf16 [(b*16+h)*64+d][4096]  (reused as kvT)
//   xb     @ 100663296  33.55MB  bf16 [16384][1024]   (kv_part f32 32MB overlays after K1)
//   Wqkvb  @ 134217728   6.29MB  bf16 [3072][1024]
//   Wob    @ 140509184   2.10MB  bf16 [1024][1024]
//   projT  @ 142606336   16KB    bf16 [128 m][64 d]
// total ~136MB.

typedef __attribute__((ext_vector_type(8))) short s8v;   // 8 x bf16 (16B)
typedef __attribute__((ext_vector_type(4))) short s4v;   // 4 x bf16 (8B)
typedef __attribute__((ext_vector_type(4))) float f32x4; // MFMA acc

#define MFMA_BF16(a, b, c) __builtin_amdgcn_mfma_f32_16x16x32_bf16((a), (b), (c), 0, 0, 0)

#define P_SCALE 0.125f                 // 1/sqrt(64)
#define F_SCALE 0.08838834764831845f   // 1/sqrt(128)

static __device__ __forceinline__ unsigned short f2bf(float f) {
  unsigned int u = __float_as_uint(f);
  u += 0x7fffu + ((u >> 16) & 1u);  // RNE
  return (unsigned short)(u >> 16);
}

// async 16B global->LDS (DMA; LDS dest = wave-uniform base + lane*16)
static __device__ __forceinline__ void gload_lds16(const void* g, void* l) {
  __builtin_amdgcn_global_load_lds(
      (const __attribute__((address_space(1))) unsigned int*)g,
      (__attribute__((address_space(3))) unsigned int*)l, 16, 0, 0);
}

// ---------------------------------------------------------------------------
// K0: fused fp32->bf16 convert for x (16M), Wq/Wk/Wv/Wo (1M each), projT.
// grid 20481: [0,16384) x; [16384,20480) weights; 20480 projT.
// ---------------------------------------------------------------------------
__global__ void conv_all_kernel(const float* __restrict__ x,
                                const float* __restrict__ Wq, const float* __restrict__ Wk,
                                const float* __restrict__ Wv, const float* __restrict__ Wo,
                                const float* __restrict__ proj,
                                short* __restrict__ xb, short* __restrict__ Wqkvb,
                                short* __restrict__ Wob, short* __restrict__ projT) {
  const int bid = blockIdx.x;
  const int t = threadIdx.x;
  if (bid < 16384) {
    int i4 = (bid * 256 + t) * 4;
    float4 f = *(const float4*)(x + i4);
    s4v v;
    v[0] = (short)f2bf(f.x); v[1] = (short)f2bf(f.y);
    v[2] = (short)f2bf(f.z); v[3] = (short)f2bf(f.w);
    *(s4v*)(xb + i4) = v;
  } else if (bid < 20480) {
    int wi = (bid - 16384) >> 10;
    int lb = (bid - 16384) & 1023;
    const float* src = (wi == 0) ? Wq : (wi == 1) ? Wk : (wi == 2) ? Wv : Wo;
    short* dst = (wi < 3) ? (Wqkvb + (size_t)wi * 1048576) : Wob;
    int i4 = (lb * 256 + t) * 4;
    float4 f = *(const float4*)(src + i4);
    s4v v;
    v[0] = (short)f2bf(f.x); v[1] = (short)f2bf(f.y);
    v[2] = (short)f2bf(f.z); v[3] = (short)f2bf(f.w);
    *(s4v*)(dst + i4) = v;
  } else {
#pragma unroll
    for (int i = 0; i < 32; ++i) {
      int idx = t + i * 256;
      int d = idx >> 7, m = idx & 127;
      projT[m * 64 + d] = (short)f2bf(proj[idx]);
    }
  }
}

// ---------------------------------------------------------------------------
// K1: qkv = xb @ Wqkv^T + bias. 128x128 tile, BK=64, bf16 MFMA,
// global_load_lds staging with XOR chunk swizzle.
// grid (128 row-tiles, 24 col-tiles). bn 0-7: q, 8-15: k, 16-23: v.
// ---------------------------------------------------------------------------
__global__ void qkv_gemm_kernel(const short* __restrict__ xb,
                                const short* __restrict__ Wqkv,
                                const float* __restrict__ bq_, const float* __restrict__ bk_,
                                const float* __restrict__ bv_,
                                short* __restrict__ qb, short* __restrict__ kb,
                                short* __restrict__ vT) {
  __shared__ __align__(16) short smem[17408];  // A[128][64]+B[128][64]; epi image [128][136]
  short* Al = smem;
  short* Bl = smem + 8192;

  const int t = threadIdx.x;
  const int bm = blockIdx.x, bn = blockIdx.y;
  const int row0 = bm * 128, n0 = bn * 128;
  const int lane = t & 63, w = t >> 6;
  const int wm = w & 1, wn = w >> 1;
  const int l15 = lane & 15, lq = lane >> 4;
  const int sx = (l15 & 7) * 8;   // fragment-read swizzle term (in shorts)

  f32x4 acc[4][4];
#pragma unroll
  for (int i = 0; i < 4; ++i)
#pragma unroll
    for (int j = 0; j < 4; ++j) acc[i][j] = (f32x4){0.f, 0.f, 0.f, 0.f};

  for (int k0 = 0; k0 < 1024; k0 += 64) {
#pragma unroll
    for (int i = 0; i < 4; ++i) {
      int c = t + i * 256;                 // chunk 0..1023
      int r = c >> 3, cl = c & 7;
      int cg = cl ^ (r & 7);               // permuted global chunk
      gload_lds16(xb   + (size_t)(row0 + r) * 1024 + k0 + cg * 8, Al + c * 8);
      gload_lds16(Wqkv + (size_t)(n0 + r) * 1024 + k0 + cg * 8, Bl + c * 8);
    }
    __syncthreads();
#pragma unroll
    for (int ks = 0; ks < 2; ++ks) {
      const int kb8 = (ks * 4 + lq) * 8;
      s8v af[4], bfr[4];
#pragma unroll
      for (int i = 0; i < 4; ++i)
        af[i] = *(s8v*)&Al[(wm * 64 + i * 16 + l15) * 64 + (kb8 ^ sx)];
#pragma unroll
      for (int j = 0; j < 4; ++j)
        bfr[j] = *(s8v*)&Bl[(wn * 64 + j * 16 + l15) * 64 + (kb8 ^ sx)];
#pragma unroll
      for (int i = 0; i < 4; ++i)
#pragma unroll
        for (int j = 0; j < 4; ++j)
          acc[i][j] = MFMA_BF16(af[i], bfr[j], acc[i][j]);
    }
    __syncthreads();
  }

  const int region = bn >> 3;  // 0 q, 1 k, 2 v
  if (region < 2) {
    const float* bias = (region == 0) ? bq_ : bk_;
    short* IM = smem;  // [128][136] natural image
#pragma unroll
    for (int j = 0; j < 4; ++j) {
      int cl = wn * 64 + j * 16 + l15;
      float bsv = bias[(n0 & 1023) + cl];
#pragma unroll
      for (int i = 0; i < 4; ++i)
#pragma unroll
        for (int r = 0; r < 4; ++r)
          IM[(wm * 64 + i * 16 + lq * 4 + r) * 136 + cl] = (short)f2bf(acc[i][j][r] + bsv);
    }
    __syncthreads();
    short* dst = (region == 0) ? qb : kb;
#pragma unroll
    for (int i = 0; i < 8; ++i) {
      int c = t + i * 256;
      int r = c >> 4, cc = c & 15;
      *(s8v*)&dst[(size_t)(row0 + r) * 1024 + (n0 & 1023) + cc * 8] =
          *(s8v*)&IM[r * 136 + cc * 8];
    }
  } else {
    short* IM = smem;  // [128 col][136] transposed image
#pragma unroll
    for (int j = 0; j < 4; ++j) {
      int cl = wn * 64 + j * 16 + l15;
      float bsv = bv_[(n0 - 2048) + cl];
#pragma unroll
      for (int i = 0; i < 4; ++i) {
        s4v pk;
#pragma unroll
        for (int r = 0; r < 4; ++r) pk[r] = (short)f2bf(acc[i][j][r] + bsv);
        *(s4v*)&IM[cl * 136 + wm * 64 + i * 16 + lq * 4] = pk;
      }
    }
    __syncthreads();
    const int b = row0 >> 12;
    const int l0 = (bm & 31) * 128;
#pragma unroll
    for (int i = 0; i < 8; ++i) {
      int c = t + i * 256;
      int ci = c >> 4, cc = c & 15;
      int cv = (bn - 16) * 128 + ci;      // 0..1023
      int grow = (b * 16 + (cv >> 6)) * 64 + (cv & 63);
      *(s8v*)&vT[(size_t)grow * 4096 + l0 + cc * 8] = *(s8v*)&IM[ci * 136 + cc * 8];
    }
  }
}

// ---------------------------------------------------------------------------
// K2: per (b,h,512-row chunk): fourier(k) -> k' ; kv_part[chunk] = k'^T @ v
// (MFMA, PRIVATE per-block output — no atomics). grid 512.
// kv_part layout: [chunk 8][bh 64][m 256][d 64] f32 (32MB, overlays dead xb).
// ---------------------------------------------------------------------------
__global__ void kv_accum_kernel(const short* __restrict__ kb, const short* __restrict__ vT,
                                const short* __restrict__ projT, float* __restrict__ kv) {
  __shared__ __align__(16) short smem[26624];  // kt[64][64]+vt[64][64]+kpT[256][72]
  short* kt = smem;
  short* vt = smem + 4096;
  short* kpT = smem + 8192;

  const int t = threadIdx.x;
  const int bid = blockIdx.x;
  const int chunk = bid & 7, h = (bid >> 3) & 15, b = bid >> 7;
  const int lane = t & 63, w = t >> 6;
  const int l15 = lane & 15, lq = lane >> 4;
  const int sx = (l15 & 7) * 8;

  s8v pf[8][2];
#pragma unroll
  for (int nt = 0; nt < 8; ++nt)
#pragma unroll
    for (int ks = 0; ks < 2; ++ks)
      pf[nt][ks] = *(const s8v*)(projT + (size_t)(nt * 16 + l15) * 64 + ks * 32 + lq * 8);

  f32x4 kvacc[4][4];
#pragma unroll
  for (int i = 0; i < 4; ++i)
#pragma unroll
    for (int j = 0; j < 4; ++j) kvacc[i][j] = (f32x4){0.f, 0.f, 0.f, 0.f};

  for (int s = 0; s < 8; ++s) {
    const int l0s = chunk * 512 + s * 64;
#pragma unroll
    for (int i = 0; i < 2; ++i) {
      int c = t + i * 256;                 // chunk 0..511
      int r = c >> 3, cl = c & 7;
      int cg = cl ^ (r & 7);
      gload_lds16(kb + (size_t)(b * 4096 + l0s + r) * 1024 + h * 64 + cg * 8, kt + c * 8);
      gload_lds16(vT + (size_t)((b * 16 + h) * 64 + r) * 4096 + l0s + cg * 8, vt + c * 8);
    }
    __syncthreads();

    // fourier: wave w rows w*16..+15
    f32x4 pacc[8];
#pragma unroll
    for (int nt = 0; nt < 8; ++nt) pacc[nt] = (f32x4){0.f, 0.f, 0.f, 0.f};
#pragma unroll
    for (int ks = 0; ks < 2; ++ks) {
      const int kb8 = (ks * 4 + lq) * 8;
      s8v af = *(s8v*)&kt[(w * 16 + l15) * 64 + (kb8 ^ sx)];
#pragma unroll
      for (int nt = 0; nt < 8; ++nt) pacc[nt] = MFMA_BF16(af, pf[nt][ks], pacc[nt]);
    }
#pragma unroll
    for (int nt = 0; nt < 8; ++nt) {
      s4v cp, sp;
#pragma unroll
      for (int r = 0; r < 4; ++r) {
        float p = pacc[nt][r] * P_SCALE;
        float sv, cv;
        __sincosf(p, &sv, &cv);
        cp[r] = (short)f2bf(cv * F_SCALE);
        sp[r] = (short)f2bf(sv * F_SCALE);
      }
      int m = nt * 16 + l15;
      int rbase = w * 16 + lq * 4;
      *(s4v*)&kpT[m * 72 + rbase] = cp;
      *(s4v*)&kpT[(m + 128) * 72 + rbase] = sp;
    }
    __syncthreads();

    // kv MFMA: wave w m-range w*64..+63
#pragma unroll
    for (int ks = 0; ks < 2; ++ks) {
      const int kb8 = (ks * 4 + lq) * 8;
      s8v af[4], bf4[4];
#pragma unroll
      for (int i = 0; i < 4; ++i)
        af[i] = *(s8v*)&kpT[(w * 64 + i * 16 + l15) * 72 + ks * 32 + lq * 8];
#pragma unroll
      for (int j = 0; j < 4; ++j)
        bf4[j] = *(s8v*)&vt[(j * 16 + l15) * 64 + (kb8 ^ sx)];
#pragma unroll
      for (int i = 0; i < 4; ++i)
#pragma unroll
        for (int j = 0; j < 4; ++j)
          kvacc[i][j] = MFMA_BF16(af[i], bf4[j], kvacc[i][j]);
    }
    __syncthreads();
  }

  // private partial: kv_part[chunk][bh][m][d], plain coalesced stores
  float* kvb = kv + (size_t)chunk * 1048576 + ((size_t)(b * 16 + h) << 14);
#pragma unroll
  for (int i = 0; i < 4; ++i)
#pragma unroll
    for (int j = 0; j < 4; ++j)
#pragma unroll
      for (int r = 0; r < 4; ++r) {
        int m = w * 64 + i * 16 + lq * 4 + r;
        int d = j * 16 + l15;
        kvb[(size_t)m * 64 + d] = kvacc[i][j][r];
      }
}

// ---------------------------------------------------------------------------
// K2.5: reduce 8 kv partials f32 -> kvT bf16 [bh*64+d][256]. grid (64,4).
// block (bh, mc) handles m in [mc*64, mc*64+64), all 64 d.
// ---------------------------------------------------------------------------
__global__ void kvT_kernel(const float* __restrict__ kvp, short* __restrict__ kvT) {
  __shared__ __align__(16) short im[4608];  // [64 d][72]
  const int t = threadIdx.x;
  const int bh = blockIdx.x, mc = blockIdx.y;
  const float* base = kvp + (size_t)bh * 16384 + (size_t)mc * 4096;
#pragma unroll
  for (int i = 0; i < 4; ++i) {
    int idx4 = t + i * 256;                // 1024 float4s = [64 m][64 d]
    int mm = idx4 >> 4, d4 = (idx4 & 15) * 4;
    float4 s = {0.f, 0.f, 0.f, 0.f};
#pragma unroll
    for (int c = 0; c < 8; ++c) {
      float4 v = *(const float4*)(base + (size_t)c * 1048576 + mm * 64 + d4);
      s.x += v.x; s.y += v.y; s.z += v.z; s.w += v.w;
    }
    im[(d4 + 0) * 72 + mm] = (short)f2bf(s.x);
    im[(d4 + 1) * 72 + mm] = (short)f2bf(s.y);
    im[(d4 + 2) * 72 + mm] = (short)f2bf(s.z);
    im[(d4 + 3) * 72 + mm] = (short)f2bf(s.w);
  }
  __syncthreads();
#pragma unroll
  for (int i = 0; i < 2; ++i) {
    int c = t + i * 256;                   // 512 stores x 16B = [64 d][64 m]
    int d = c >> 3, mm8 = (c & 7) * 8;
    *(s8v*)&kvT[(size_t)(bh * 64 + d) * 256 + mc * 64 + mm8] = *(s8v*)&im[d * 72 + mm8];
  }
}

// ---------------------------------------------------------------------------
// K3: fourier(q) + attn = q' @ kv, per (64-row tile, head). grid (256,16).
// kvT (32KB/head, L2-resident) read DIRECT from global — no LDS staging,
// no per-half barriers (qA rows are wave-private).
// ---------------------------------------------------------------------------
__global__ void attn_kernel(const short* __restrict__ qb, const short* __restrict__ projT,
                            const short* __restrict__ kvT, short* __restrict__ attnb) {
  __shared__ __align__(16) short smem[12800];  // qt[64][64]=4096 + qA[64][136]=8704
  short* qt = smem;
  short* qA = smem + 4096;

  const int t = threadIdx.x;
  const int rt = blockIdx.x, h = blockIdx.y;
  const int row0 = rt * 64;
  const int b = row0 >> 12;
  const int lane = t & 63, w = t >> 6;
  const int l15 = lane & 15, lq = lane >> 4;
  const int sx = (l15 & 7) * 8;

  s8v pf[8][2];
#pragma unroll
  for (int nt = 0; nt < 8; ++nt)
#pragma unroll
    for (int ks = 0; ks < 2; ++ks)
      pf[nt][ks] = *(const s8v*)(projT + (size_t)(nt * 16 + l15) * 64 + ks * 32 + lq * 8);

#pragma unroll
  for (int i = 0; i < 2; ++i) {
    int c = t + i * 256;
    int r = c >> 3, cl = c & 7;
    int cg = cl ^ (r & 7);
    gload_lds16(qb + (size_t)(row0 + r) * 1024 + h * 64 + cg * 8, qt + c * 8);
  }
  __syncthreads();

  f32x4 pacc[8];
#pragma unroll
  for (int nt = 0; nt < 8; ++nt) pacc[nt] = (f32x4){0.f, 0.f, 0.f, 0.f};
#pragma unroll
  for (int ks = 0; ks < 2; ++ks) {
    const int kb8 = (ks * 4 + lq) * 8;
    s8v af = *(s8v*)&qt[(w * 16 + l15) * 64 + (kb8 ^ sx)];
#pragma unroll
    for (int nt = 0; nt < 8; ++nt) pacc[nt] = MFMA_BF16(af, pf[nt][ks], pacc[nt]);
  }

  const short* kvbase = kvT + ((size_t)(b * 16 + h) * 64) * 256;

  f32x4 aacc[4];
#pragma unroll
  for (int j = 0; j < 4; ++j) aacc[j] = (f32x4){0.f, 0.f, 0.f, 0.f};

#pragma unroll
  for (int half = 0; half < 2; ++half) {
    // q' half -> qA [64][136] (wave-private rows; no barrier needed)
#pragma unroll
    for (int nt = 0; nt < 8; ++nt)
#pragma unroll
      for (int r = 0; r < 4; ++r) {
        float p = pacc[nt][r] * P_SCALE;
        float fv = (half == 0) ? __cosf(p) : __sinf(p);
        qA[(w * 16 + lq * 4 + r) * 136 + nt * 16 + l15] = (short)f2bf(fv * F_SCALE);
      }
#pragma unroll
    for (int ks = 0; ks < 4; ++ks) {
      s8v af = *(s8v*)&qA[(w * 16 + l15) * 136 + ks * 32 + lq * 8];
#pragma unroll
      for (int j = 0; j < 4; ++j) {
        s8v bf4 = *(const s8v*)&kvbase[(size_t)(j * 16 + l15) * 256 + half * 128 +
                                       (ks * 4 + lq) * 8];
        aacc[j] = MFMA_BF16(af, bf4, aacc[j]);
      }
    }
  }

  // epilogue image at smem base [64][72] (overlaps qt+qA head — barrier first)
  __syncthreads();
#pragma unroll
  for (int j = 0; j < 4; ++j)
#pragma unroll
    for (int r = 0; r < 4; ++r)
      smem[(w * 16 + lq * 4 + r) * 72 + j * 16 + l15] = (short)f2bf(aacc[j][r]);
  __syncthreads();
#pragma unroll
  for (int i = 0; i < 2; ++i) {
    int c = t + i * 256;
    int r = c >> 3, cc = c & 7;
    *(s8v*)&attnb[(size_t)(row0 + r) * 1024 + h * 64 + cc * 8] = *(s8v*)&smem[r * 72 + cc * 8];
  }
}

// ---------------------------------------------------------------------------
// K4: out = attn @ Wo^T + bo. fp32 out. grid (128, 8).
// ---------------------------------------------------------------------------
__global__ void out_gemm_kernel(const short* __restrict__ attnb, const short* __restrict__ Wob,
                                const float* __restrict__ bo_, float* __restrict__ out) {
  __shared__ __align__(16) short smem[16384];
  short* Al = smem;
  short* Bl = smem + 8192;

  const int t = threadIdx.x;
  const int bm = blockIdx.x, bn = blockIdx.y;
  const int row0 = bm * 128, n0 = bn * 128;
  const int lane = t & 63, w = t >> 6;
  const int wm = w & 1, wn = w >> 1;
  const int l15 = lane & 15, lq = lane >> 4;
  const int sx = (l15 & 7) * 8;

  f32x4 acc[4][4];
#pragma unroll
  for (int i = 0; i < 4; ++i)
#pragma unroll
    for (int j = 0; j < 4; ++j) acc[i][j] = (f32x4){0.f, 0.f, 0.f, 0.f};

  for (int k0 = 0; k0 < 1024; k0 += 64) {
#pragma unroll
    for (int i = 0; i < 4; ++i) {
      int c = t + i * 256;
      int r = c >> 3, cl = c & 7;
      int cg = cl ^ (r & 7);
      gload_lds16(attnb + (size_t)(row0 + r) * 1024 + k0 + cg * 8, Al + c * 8);
      gload_lds16(Wob   + (size_t)(n0 + r) * 1024 + k0 + cg * 8, Bl + c * 8);
    }
    __syncthreads();
#pragma unroll
    for (int ks = 0; ks < 2; ++ks) {
      const int kb8 = (ks * 4 + lq) * 8;
      s8v af[4], bfr[4];
#pragma unroll
      for (int i = 0; i < 4; ++i)
        af[i] = *(s8v*)&Al[(wm * 64 + i * 16 + l15) * 64 + (kb8 ^ sx)];
#pragma unroll
      for (int j = 0; j < 4; ++j)
        bfr[j] = *(s8v*)&Bl[(wn * 64 + j * 16 + l15) * 64 + (kb8 ^ sx)];
#pragma unroll
      for (int i = 0; i < 4; ++i)
#pragma unroll
        for (int j = 0; j < 4; ++j)
          acc[i][j] = MFMA_BF16(af[i], bfr[j], acc[i][j]);
    }
    __syncthreads();
  }

#pragma unroll
  for (int j = 0; j < 4; ++j) {
    int cl = wn * 64 + j * 16 + l15;
    float bsv = bo_[n0 + cl];
#pragma unroll
    for (int i = 0; i < 4; ++i)
#pragma unroll
      for (int r = 0; r < 4; ++r)
        out[(size_t)(row0 + wm * 64 + i * 16 + lq * 4 + r) * 1024 + n0 + cl] =
            acc[i][j][r] + bsv;
  }
}

// ---------------------------------------------------------------------------
extern "C" void kernel_launch(void* const* d_in, const int* in_sizes, int n_in,
                              void* d_out, int out_size, void* d_ws, size_t ws_size,
                              hipStream_t stream) {
  const float* x    = (const float*)d_in[0];
  const float* proj = (const float*)d_in[1];
  const float* Wq   = (const float*)d_in[2];
  const float* bq   = (const float*)d_in[3];
  const float* Wk   = (const float*)d_in[4];
  const float* bk   = (const float*)d_in[5];
  const float* Wv   = (const float*)d_in[6];
  const float* bv   = (const float*)d_in[7];
  const float* Wo   = (const float*)d_in[8];
  const float* bo   = (const float*)d_in[9];
  float* out = (float*)d_out;

  char* wsb = (char*)d_ws;
  short* qb    = (short*)(wsb + 0);
  short* kb    = (short*)(wsb + 33554432);
  short* vT    = (short*)(wsb + 67108864);
  short* xb    = (short*)(wsb + 100663296);
  short* Wqkvb = (short*)(wsb + 134217728);
  short* Wob   = (short*)(wsb + 140509184);
  short* projT = (short*)(wsb + 142606336);
  float* kv_part = (float*)(wsb + 100663296);  // 32MB, overlays xb (dead after K1)
  short* attnb = kb;                            // kb dead after K2
  short* kvT   = vT;                            // vT dead after K2

  conv_all_kernel<<<dim3(20481), dim3(256), 0, stream>>>(
      x, Wq, Wk, Wv, Wo, proj, xb, Wqkvb, Wob, projT);

  qkv_gemm_kernel<<<dim3(128, 24), dim3(256), 0, stream>>>(xb, Wqkvb, bq, bk, bv, qb, kb, vT);
  kv_accum_kernel<<<dim3(512), dim3(256), 0, stream>>>(kb, vT, projT, kv_part);
  kvT_kernel<<<dim3(64, 4), dim3(256), 0, stream>>>(kv_part, kvT);
  attn_kernel<<<dim3(256, 16), dim3(256), 0, stream>>>(qb, projT, kvT, attnb);
  out_gemm_kernel<<<dim3(128, 8), dim3(256), 0, stream>>>(attnb, Wob, bo, out);
}

// Round 3
// 417.751 us; speedup vs baseline: 1.0654x; 1.0654x over previous
//
#include <hip/hip_runtime.h>
#include <cstddef>
#include <cstdint>

// LinearAttention — bf16 MFMA. B=4 L=4096 D=1024 H=16 d=64 M=128 (2M=256).
// K0 fused convert -> K1 fused QKV GEMM (256^2 8-phase, counted vmcnt)
// -> K2 fourier(k)+kv outer (private partials) -> K2.5 reduce+transpose
// -> K3 fourier(q)+attn (LDS-staged kvT, round-1 version) -> K4 out GEMM.
//
// ws layout (bytes):
//   qb     @ 0          33.55MB  bf16 [16384][1024]
//   kb     @ 33554432   33.55MB  bf16 [16384][1024]   (reused as attnb)
//   vT     @ 67108864   33.55MB  bf16 [(b*16+h)*64+d][4096]  (reused as kvT)
//   xb     @ 100663296  33.55MB  bf16 [16384][1024]   (kv_part f32 32MB overlays after K1)
//   Wqkvb  @ 134217728   6.29MB  bf16 [3072][1024]
//   Wob    @ 140509184   2.10MB  bf16 [1024][1024]
//   projT  @ 142606336   16KB    bf16 [128 m][64 d]

typedef __attribute__((ext_vector_type(8))) short s8v;   // 8 x bf16 (16B)
typedef __attribute__((ext_vector_type(4))) short s4v;   // 4 x bf16 (8B)
typedef __attribute__((ext_vector_type(4))) float f32x4; // MFMA acc

#define MFMA_BF16(a, b, c) __builtin_amdgcn_mfma_f32_16x16x32_bf16((a), (b), (c), 0, 0, 0)

#define P_SCALE 0.125f                 // 1/sqrt(64)
#define F_SCALE 0.08838834764831845f   // 1/sqrt(128)

static __device__ __forceinline__ unsigned short f2bf(float f) {
  unsigned int u = __float_as_uint(f);
  u += 0x7fffu + ((u >> 16) & 1u);  // RNE
  return (unsigned short)(u >> 16);
}

// async 16B global->LDS (DMA; LDS dest = wave-uniform base + lane*16)
static __device__ __forceinline__ void gload_lds16(const void* g, void* l) {
  __builtin_amdgcn_global_load_lds(
      (const __attribute__((address_space(1))) unsigned int*)g,
      (__attribute__((address_space(3))) unsigned int*)l, 16, 0, 0);
}

// ---------------------------------------------------------------------------
// K0: fused fp32->bf16 convert for x (16M), Wq/Wk/Wv/Wo (1M each), projT.
// ---------------------------------------------------------------------------
__global__ void conv_all_kernel(const float* __restrict__ x,
                                const float* __restrict__ Wq, const float* __restrict__ Wk,
                                const float* __restrict__ Wv, const float* __restrict__ Wo,
                                const float* __restrict__ proj,
                                short* __restrict__ xb, short* __restrict__ Wqkvb,
                                short* __restrict__ Wob, short* __restrict__ projT) {
  const int bid = blockIdx.x;
  const int t = threadIdx.x;
  if (bid < 16384) {
    int i4 = (bid * 256 + t) * 4;
    float4 f = *(const float4*)(x + i4);
    s4v v;
    v[0] = (short)f2bf(f.x); v[1] = (short)f2bf(f.y);
    v[2] = (short)f2bf(f.z); v[3] = (short)f2bf(f.w);
    *(s4v*)(xb + i4) = v;
  } else if (bid < 20480) {
    int wi = (bid - 16384) >> 10;
    int lb = (bid - 16384) & 1023;
    const float* src = (wi == 0) ? Wq : (wi == 1) ? Wk : (wi == 2) ? Wv : Wo;
    short* dst = (wi < 3) ? (Wqkvb + (size_t)wi * 1048576) : Wob;
    int i4 = (lb * 256 + t) * 4;
    float4 f = *(const float4*)(src + i4);
    s4v v;
    v[0] = (short)f2bf(f.x); v[1] = (short)f2bf(f.y);
    v[2] = (short)f2bf(f.z); v[3] = (short)f2bf(f.w);
    *(s4v*)(dst + i4) = v;
  } else {
#pragma unroll
    for (int i = 0; i < 32; ++i) {
      int idx = t + i * 256;
      int d = idx >> 7, m = idx & 127;
      projT[m * 64 + d] = (short)f2bf(proj[idx]);
    }
  }
}

// ---------------------------------------------------------------------------
// K1: qkv = xb @ Wqkv^T + bias. 256x256 tile, BK=64, 8-phase schedule,
// counted vmcnt(4), raw s_barrier, setprio around MFMA clusters.
// grid (64 row-tiles, 12 col-tiles), 512 threads. bn 0-3: q, 4-7: k, 8-11: v.
// LDS: 2 dbuf x (A[2 half][128][64] + B[2 half][128][64]) = 128 KiB.
// Per phase: all 8 waves compute a 64x32 piece of ONE 128x128 block-quadrant
// (mh,nh) -> every wave consumes the same A-half/B-half => counted waits are
// sound. Stage order A0,B0,B1,A1 matches quadrant first-use (00,01,10,11).
// ---------------------------------------------------------------------------
__global__ __launch_bounds__(512, 2) void qkv_gemm256_kernel(
    const short* __restrict__ xb, const short* __restrict__ Wqkv,
    const float* __restrict__ bq_, const float* __restrict__ bk_,
    const float* __restrict__ bv_,
    short* __restrict__ qb, short* __restrict__ kb, short* __restrict__ vT) {
  __shared__ __align__(16) short sm[65536];  // 128 KiB

  const int t = threadIdx.x;
  const int bm = blockIdx.x, bn = blockIdx.y;
  const int row0 = bm * 256, n0 = bn * 256;
  const int lane = t & 63, w = t >> 6;
  const int wr = w >> 2, wc = w & 3;
  const int l15 = lane & 15, lq = lane >> 4;
  const int sx = (l15 & 7) * 8;

  f32x4 acc[4][4][2];
#pragma unroll
  for (int q = 0; q < 4; ++q)
#pragma unroll
    for (int i = 0; i < 4; ++i)
#pragma unroll
      for (int j = 0; j < 2; ++j) acc[q][i][j] = (f32x4){0.f, 0.f, 0.f, 0.f};

  // stage one 128-row half-tile (16KB): 512 thr x 2 x 16B
#define STAGE_A(mh, k0v, pp) {                                                  \
    short* dsth = sm + (pp) * 32768 + (mh) * 8192;                              \
    _Pragma("unroll") for (int ii = 0; ii < 2; ++ii) {                          \
      int c = t + ii * 512; int r = c >> 3, cl = c & 7, cg = cl ^ (r & 7);      \
      gload_lds16(xb + (size_t)(row0 + (mh) * 128 + r) * 1024 + (k0v) + cg * 8, \
                  dsth + c * 8);                                                \
    } }
#define STAGE_B(nh, k0v, pp) {                                                  \
    short* dsth = sm + (pp) * 32768 + 16384 + (nh) * 8192;                      \
    _Pragma("unroll") for (int ii = 0; ii < 2; ++ii) {                          \
      int c = t + ii * 512; int r = c >> 3, cl = c & 7, cg = cl ^ (r & 7);      \
      gload_lds16(Wqkv + (size_t)(n0 + (nh) * 128 + r) * 1024 + (k0v) + cg * 8, \
                  dsth + c * 8);                                                \
    } }
#define VM4 asm volatile("s_waitcnt vmcnt(4)" ::: "memory")
#define VM0 asm volatile("s_waitcnt vmcnt(0)" ::: "memory")

#define PHASE(mh, nh, STAGE_STMT, WAIT_STMT, SYNC) {                            \
    const short* Ah = sm + p * 32768 + (mh) * 8192;                             \
    const short* Bh = sm + p * 32768 + 16384 + (nh) * 8192;                     \
    s8v af[4][2], bfr[2][2];                                                    \
    _Pragma("unroll") for (int i = 0; i < 4; ++i)                               \
      _Pragma("unroll") for (int ks = 0; ks < 2; ++ks)                          \
        af[i][ks] = *(const s8v*)&Ah[(wr * 64 + i * 16 + l15) * 64 +            \
                                     (((ks * 4 + lq) * 8) ^ sx)];               \
    _Pragma("unroll") for (int j = 0; j < 2; ++j)                               \
      _Pragma("unroll") for (int ks = 0; ks < 2; ++ks)                          \
        bfr[j][ks] = *(const s8v*)&Bh[(wc * 32 + j * 16 + l15) * 64 +           \
                                      (((ks * 4 + lq) * 8) ^ sx)];              \
    STAGE_STMT;                                                                 \
    WAIT_STMT;                                                                  \
    if (SYNC) __builtin_amdgcn_s_barrier();                                     \
    asm volatile("s_waitcnt lgkmcnt(0)" ::: "memory");                          \
    __builtin_amdgcn_s_setprio(1);                                              \
    _Pragma("unroll") for (int ks = 0; ks < 2; ++ks)                            \
      _Pragma("unroll") for (int i = 0; i < 4; ++i)                             \
        _Pragma("unroll") for (int j = 0; j < 2; ++j)                           \
          acc[(mh) * 2 + (nh)][i][j] =                                          \
              MFMA_BF16(af[i][ks], bfr[j][ks], acc[(mh) * 2 + (nh)][i][j]);     \
    __builtin_amdgcn_s_setprio(0);                                              \
    if (SYNC) __builtin_amdgcn_s_barrier();                                     \
  }

  // prologue: stage K-tile 0 (A0,B0,B1,A1), ensure A0+B0 landed
  STAGE_A(0, 0, 0);
  STAGE_B(0, 0, 0);
  STAGE_B(1, 0, 0);
  STAGE_A(1, 0, 0);
  VM4;
  __builtin_amdgcn_s_barrier();

  int p = 0;
  for (int tt = 0; tt < 15; ++tt) {
    const int k1 = (tt + 1) * 64;
    PHASE(0, 0, STAGE_A(0, k1, p ^ 1), VM4, 1);
    PHASE(0, 1, STAGE_B(0, k1, p ^ 1), VM4, 1);
    PHASE(1, 0, STAGE_B(1, k1, p ^ 1), { }, 1);
    PHASE(1, 1, STAGE_A(1, k1, p ^ 1), VM4, 1);
    p ^= 1;
  }
  // K-tile 15: drain once, compute barrier-free
  VM0;
  __builtin_amdgcn_s_barrier();
  PHASE(0, 0, { }, { }, 0);
  PHASE(0, 1, { }, { }, 0);
  PHASE(1, 0, { }, { }, 0);
  PHASE(1, 1, { }, { }, 0);

  // -------- epilogue --------
  __builtin_amdgcn_s_barrier();
  short* im = sm;  // image [128][264] (q/k: rows x cols; v: cols x rows)
  const int region = bn >> 2;  // 0 q, 1 k, 2 v
  if (region < 2) {
    const float* bias = (region == 0) ? bq_ : bk_;
    short* dst = (region == 0) ? qb : kb;
    const int cb = (bn & 3) * 256;
#pragma unroll
    for (int mh = 0; mh < 2; ++mh) {
#pragma unroll
      for (int nh = 0; nh < 2; ++nh)
#pragma unroll
        for (int j = 0; j < 2; ++j) {
          int cl = nh * 128 + wc * 32 + j * 16 + l15;
          float bsv = bias[cb + cl];
#pragma unroll
          for (int i = 0; i < 4; ++i)
#pragma unroll
            for (int r = 0; r < 4; ++r)
              im[(wr * 64 + i * 16 + lq * 4 + r) * 264 + cl] =
                  (short)f2bf(acc[mh * 2 + nh][i][j][r] + bsv);
        }
      __builtin_amdgcn_s_barrier();
#pragma unroll
      for (int i = 0; i < 8; ++i) {
        int c = t + i * 512;
        int r = c >> 5, cc = c & 31;
        *(s8v*)&dst[(size_t)(row0 + mh * 128 + r) * 1024 + cb + cc * 8] =
            *(s8v*)&im[r * 264 + cc * 8];
      }
      __builtin_amdgcn_s_barrier();
    }
  } else {
    const int b = bm >> 4;
    const int l0 = (bm & 15) * 256;
#pragma unroll
    for (int nh = 0; nh < 2; ++nh) {
#pragma unroll
      for (int mh = 0; mh < 2; ++mh)
#pragma unroll
        for (int j = 0; j < 2; ++j) {
          int cl = wc * 32 + j * 16 + l15;  // 0..127 within nh
          float bsv = bv_[(bn - 8) * 256 + nh * 128 + cl];
#pragma unroll
          for (int i = 0; i < 4; ++i) {
            s4v pk;
#pragma unroll
            for (int r = 0; r < 4; ++r)
              pk[r] = (short)f2bf(acc[mh * 2 + nh][i][j][r] + bsv);
            *(s4v*)&im[cl * 264 + mh * 128 + wr * 64 + i * 16 + lq * 4] = pk;
          }
        }
      __builtin_amdgcn_s_barrier();
#pragma unroll
      for (int i = 0; i < 8; ++i) {
        int c = t + i * 512;
        int cp = c >> 5, rr8 = (c & 31) * 8;
        int cv = (bn - 8) * 256 + nh * 128 + cp;
        int grow = (b * 16 + (cv >> 6)) * 64 + (cv & 63);
        *(s8v*)&vT[(size_t)grow * 4096 + l0 + rr8] = *(s8v*)&im[cp * 264 + rr8];
      }
      __builtin_amdgcn_s_barrier();
    }
  }
#undef STAGE_A
#undef STAGE_B
#undef VM4
#undef VM0
#undef PHASE
}

// ---------------------------------------------------------------------------
// K2: per (b,h,512-row chunk): fourier(k) -> k' ; kv_part[chunk] = k'^T @ v
// (MFMA, PRIVATE per-block output — no atomics). grid 512.
// kv_part layout: [chunk 8][bh 64][m 256][d 64] f32 (32MB, overlays dead xb).
// ---------------------------------------------------------------------------
__global__ void kv_accum_kernel(const short* __restrict__ kb, const short* __restrict__ vT,
                                const short* __restrict__ projT, float* __restrict__ kv) {
  __shared__ __align__(16) short smem[26624];  // kt[64][64]+vt[64][64]+kpT[256][72]
  short* kt = smem;
  short* vt = smem + 4096;
  short* kpT = smem + 8192;

  const int t = threadIdx.x;
  const int bid = blockIdx.x;
  const int chunk = bid & 7, h = (bid >> 3) & 15, b = bid >> 7;
  const int lane = t & 63, w = t >> 6;
  const int l15 = lane & 15, lq = lane >> 4;
  const int sx = (l15 & 7) * 8;

  s8v pf[8][2];
#pragma unroll
  for (int nt = 0; nt < 8; ++nt)
#pragma unroll
    for (int ks = 0; ks < 2; ++ks)
      pf[nt][ks] = *(const s8v*)(projT + (size_t)(nt * 16 + l15) * 64 + ks * 32 + lq * 8);

  f32x4 kvacc[4][4];
#pragma unroll
  for (int i = 0; i < 4; ++i)
#pragma unroll
    for (int j = 0; j < 4; ++j) kvacc[i][j] = (f32x4){0.f, 0.f, 0.f, 0.f};

  for (int s = 0; s < 8; ++s) {
    const int l0s = chunk * 512 + s * 64;
#pragma unroll
    for (int i = 0; i < 2; ++i) {
      int c = t + i * 256;                 // chunk 0..511
      int r = c >> 3, cl = c & 7;
      int cg = cl ^ (r & 7);
      gload_lds16(kb + (size_t)(b * 4096 + l0s + r) * 1024 + h * 64 + cg * 8, kt + c * 8);
      gload_lds16(vT + (size_t)((b * 16 + h) * 64 + r) * 4096 + l0s + cg * 8, vt + c * 8);
    }
    __syncthreads();

    // fourier: wave w rows w*16..+15
    f32x4 pacc[8];
#pragma unroll
    for (int nt = 0; nt < 8; ++nt) pacc[nt] = (f32x4){0.f, 0.f, 0.f, 0.f};
#pragma unroll
    for (int ks = 0; ks < 2; ++ks) {
      const int kb8 = (ks * 4 + lq) * 8;
      s8v af = *(s8v*)&kt[(w * 16 + l15) * 64 + (kb8 ^ sx)];
#pragma unroll
      for (int nt = 0; nt < 8; ++nt) pacc[nt] = MFMA_BF16(af, pf[nt][ks], pacc[nt]);
    }
#pragma unroll
    for (int nt = 0; nt < 8; ++nt) {
      s4v cp, sp;
#pragma unroll
      for (int r = 0; r < 4; ++r) {
        float pv = pacc[nt][r] * P_SCALE;
        float sv, cv;
        __sincosf(pv, &sv, &cv);
        cp[r] = (short)f2bf(cv * F_SCALE);
        sp[r] = (short)f2bf(sv * F_SCALE);
      }
      int m = nt * 16 + l15;
      int rbase = w * 16 + lq * 4;
      *(s4v*)&kpT[m * 72 + rbase] = cp;
      *(s4v*)&kpT[(m + 128) * 72 + rbase] = sp;
    }
    __syncthreads();

    // kv MFMA: wave w m-range w*64..+63
#pragma unroll
    for (int ks = 0; ks < 2; ++ks) {
      const int kb8 = (ks * 4 + lq) * 8;
      s8v af[4], bf4[4];
#pragma unroll
      for (int i = 0; i < 4; ++i)
        af[i] = *(s8v*)&kpT[(w * 64 + i * 16 + l15) * 72 + ks * 32 + lq * 8];
#pragma unroll
      for (int j = 0; j < 4; ++j)
        bf4[j] = *(s8v*)&vt[(j * 16 + l15) * 64 + (kb8 ^ sx)];
#pragma unroll
      for (int i = 0; i < 4; ++i)
#pragma unroll
        for (int j = 0; j < 4; ++j)
          kvacc[i][j] = MFMA_BF16(af[i], bf4[j], kvacc[i][j]);
    }
    __syncthreads();
  }

  // private partial: kv_part[chunk][bh][m][d], plain coalesced stores
  float* kvb = kv + (size_t)chunk * 1048576 + ((size_t)(b * 16 + h) << 14);
#pragma unroll
  for (int i = 0; i < 4; ++i)
#pragma unroll
    for (int j = 0; j < 4; ++j)
#pragma unroll
      for (int r = 0; r < 4; ++r) {
        int m = w * 64 + i * 16 + lq * 4 + r;
        int d = j * 16 + l15;
        kvb[(size_t)m * 64 + d] = kvacc[i][j][r];
      }
}

// ---------------------------------------------------------------------------
// K2.5: reduce 8 kv partials f32 -> kvT bf16 [bh*64+d][256]. grid (64,4).
// ---------------------------------------------------------------------------
__global__ void kvT_kernel(const float* __restrict__ kvp, short* __restrict__ kvT) {
  __shared__ __align__(16) short im[4608];  // [64 d][72]
  const int t = threadIdx.x;
  const int bh = blockIdx.x, mc = blockIdx.y;
  const float* base = kvp + (size_t)bh * 16384 + (size_t)mc * 4096;
#pragma unroll
  for (int i = 0; i < 4; ++i) {
    int idx4 = t + i * 256;                // 1024 float4s = [64 m][64 d]
    int mm = idx4 >> 4, d4 = (idx4 & 15) * 4;
    float4 s = {0.f, 0.f, 0.f, 0.f};
#pragma unroll
    for (int c = 0; c < 8; ++c) {
      float4 v = *(const float4*)(base + (size_t)c * 1048576 + mm * 64 + d4);
      s.x += v.x; s.y += v.y; s.z += v.z; s.w += v.w;
    }
    im[(d4 + 0) * 72 + mm] = (short)f2bf(s.x);
    im[(d4 + 1) * 72 + mm] = (short)f2bf(s.y);
    im[(d4 + 2) * 72 + mm] = (short)f2bf(s.z);
    im[(d4 + 3) * 72 + mm] = (short)f2bf(s.w);
  }
  __syncthreads();
#pragma unroll
  for (int i = 0; i < 2; ++i) {
    int c = t + i * 256;                   // 512 stores x 16B = [64 d][64 m]
    int d = c >> 3, mm8 = (c & 7) * 8;
    *(s8v*)&kvT[(size_t)(bh * 64 + d) * 256 + mc * 64 + mm8] = *(s8v*)&im[d * 72 + mm8];
  }
}

// ---------------------------------------------------------------------------
// K3: fourier(q) + attn = q' @ kv, per (64-row tile, head). grid (256,16).
// Round-1 version: kvT staged via global_load_lds (XOR-swizzled).
// ---------------------------------------------------------------------------
__global__ void attn_kernel(const short* __restrict__ qb, const short* __restrict__ projT,
                            const short* __restrict__ kvT, short* __restrict__ attnb) {
  __shared__ __align__(16) short smem[20992];  // qt[64][64]+qA[64][136]+kvt[64][128]
  short* qt = smem;
  short* qA = smem + 4096;
  short* kvt = smem + 12800;

  const int t = threadIdx.x;
  const int rt = blockIdx.x, h = blockIdx.y;
  const int row0 = rt * 64;
  const int b = row0 >> 12;
  const int lane = t & 63, w = t >> 6;
  const int l15 = lane & 15, lq = lane >> 4;
  const int sx = (l15 & 7) * 8;

  s8v pf[8][2];
#pragma unroll
  for (int nt = 0; nt < 8; ++nt)
#pragma unroll
    for (int ks = 0; ks < 2; ++ks)
      pf[nt][ks] = *(const s8v*)(projT + (size_t)(nt * 16 + l15) * 64 + ks * 32 + lq * 8);

#pragma unroll
  for (int i = 0; i < 2; ++i) {
    int c = t + i * 256;
    int r = c >> 3, cl = c & 7;
    int cg = cl ^ (r & 7);
    gload_lds16(qb + (size_t)(row0 + r) * 1024 + h * 64 + cg * 8, qt + c * 8);
  }
  __syncthreads();

  f32x4 pacc[8];
#pragma unroll
  for (int nt = 0; nt < 8; ++nt) pacc[nt] = (f32x4){0.f, 0.f, 0.f, 0.f};
#pragma unroll
  for (int ks = 0; ks < 2; ++ks) {
    const int kb8 = (ks * 4 + lq) * 8;
    s8v af = *(s8v*)&qt[(w * 16 + l15) * 64 + (kb8 ^ sx)];
#pragma unroll
    for (int nt = 0; nt < 8; ++nt) pacc[nt] = MFMA_BF16(af, pf[nt][ks], pacc[nt]);
  }

  f32x4 aacc[4];
#pragma unroll
  for (int j = 0; j < 4; ++j) aacc[j] = (f32x4){0.f, 0.f, 0.f, 0.f};

#pragma unroll
  for (int half = 0; half < 2; ++half) {
    // q' half -> qA [64][136]
#pragma unroll
    for (int nt = 0; nt < 8; ++nt)
#pragma unroll
      for (int r = 0; r < 4; ++r) {
        float p = pacc[nt][r] * P_SCALE;
        float fv = (half == 0) ? __cosf(p) : __sinf(p);
        qA[(w * 16 + lq * 4 + r) * 136 + nt * 16 + l15] = (short)f2bf(fv * F_SCALE);
      }
    // stage kvT half: [64 d][128 m'], swizzled (16 chunks/row)
#pragma unroll
    for (int i = 0; i < 4; ++i) {
      int c = t + i * 256;                 // chunk 0..1023
      int d = c >> 4, cl = c & 15;
      int cg = cl ^ (d & 15);
      gload_lds16(kvT + (size_t)((b * 16 + h) * 64 + d) * 256 + half * 128 + cg * 8,
                  kvt + c * 8);
    }
    __syncthreads();
#pragma unroll
    for (int ks = 0; ks < 4; ++ks) {
      s8v af = *(s8v*)&qA[(w * 16 + l15) * 136 + ks * 32 + lq * 8];
#pragma unroll
      for (int j = 0; j < 4; ++j) {
        int row = j * 16 + l15;
        s8v bf4 = *(s8v*)&kvt[row * 128 + (((ks * 4 + lq) ^ l15) * 8)];
        aacc[j] = MFMA_BF16(af, bf4, aacc[j]);
      }
    }
    __syncthreads();
  }

  // epilogue image at smem base [64][72]
#pragma unroll
  for (int j = 0; j < 4; ++j)
#pragma unroll
    for (int r = 0; r < 4; ++r)
      smem[(w * 16 + lq * 4 + r) * 72 + j * 16 + l15] = (short)f2bf(aacc[j][r]);
  __syncthreads();
#pragma unroll
  for (int i = 0; i < 2; ++i) {
    int c = t + i * 256;
    int r = c >> 3, cc = c & 7;
    *(s8v*)&attnb[(size_t)(row0 + r) * 1024 + h * 64 + cc * 8] = *(s8v*)&smem[r * 72 + cc * 8];
  }
}

// ---------------------------------------------------------------------------
// K4: out = attn @ Wo^T + bo. fp32 out. grid (128, 8).
// ---------------------------------------------------------------------------
__global__ void out_gemm_kernel(const short* __restrict__ attnb, const short* __restrict__ Wob,
                                const float* __restrict__ bo_, float* __restrict__ out) {
  __shared__ __align__(16) short smem[16384];
  short* Al = smem;
  short* Bl = smem + 8192;

  const int t = threadIdx.x;
  const int bm = blockIdx.x, bn = blockIdx.y;
  const int row0 = bm * 128, n0 = bn * 128;
  const int lane = t & 63, w = t >> 6;
  const int wm = w & 1, wn = w >> 1;
  const int l15 = lane & 15, lq = lane >> 4;
  const int sx = (l15 & 7) * 8;

  f32x4 acc[4][4];
#pragma unroll
  for (int i = 0; i < 4; ++i)
#pragma unroll
    for (int j = 0; j < 4; ++j) acc[i][j] = (f32x4){0.f, 0.f, 0.f, 0.f};

  for (int k0 = 0; k0 < 1024; k0 += 64) {
#pragma unroll
    for (int i = 0; i < 4; ++i) {
      int c = t + i * 256;
      int r = c >> 3, cl = c & 7;
      int cg = cl ^ (r & 7);
      gload_lds16(attnb + (size_t)(row0 + r) * 1024 + k0 + cg * 8, Al + c * 8);
      gload_lds16(Wob   + (size_t)(n0 + r) * 1024 + k0 + cg * 8, Bl + c * 8);
    }
    __syncthreads();
#pragma unroll
    for (int ks = 0; ks < 2; ++ks) {
      const int kb8 = (ks * 4 + lq) * 8;
      s8v af[4], bfr[4];
#pragma unroll
      for (int i = 0; i < 4; ++i)
        af[i] = *(s8v*)&Al[(wm * 64 + i * 16 + l15) * 64 + (kb8 ^ sx)];
#pragma unroll
      for (int j = 0; j < 4; ++j)
        bfr[j] = *(s8v*)&Bl[(wn * 64 + j * 16 + l15) * 64 + (kb8 ^ sx)];
#pragma unroll
      for (int i = 0; i < 4; ++i)
#pragma unroll
        for (int j = 0; j < 4; ++j)
          acc[i][j] = MFMA_BF16(af[i], bfr[j], acc[i][j]);
    }
    __syncthreads();
  }

#pragma unroll
  for (int j = 0; j < 4; ++j) {
    int cl = wn * 64 + j * 16 + l15;
    float bsv = bo_[n0 + cl];
#pragma unroll
    for (int i = 0; i < 4; ++i)
#pragma unroll
      for (int r = 0; r < 4; ++r)
        out[(size_t)(row0 + wm * 64 + i * 16 + lq * 4 + r) * 1024 + n0 + cl] =
            acc[i][j][r] + bsv;
  }
}

// ---------------------------------------------------------------------------
extern "C" void kernel_launch(void* const* d_in, const int* in_sizes, int n_in,
                              void* d_out, int out_size, void* d_ws, size_t ws_size,
                              hipStream_t stream) {
  const float* x    = (const float*)d_in[0];
  const float* proj = (const float*)d_in[1];
  const float* Wq   = (const float*)d_in[2];
  const float* bq   = (const float*)d_in[3];
  const float* Wk   = (const float*)d_in[4];
  const float* bk   = (const float*)d_in[5];
  const float* Wv   = (const float*)d_in[6];
  const float* bv   = (const float*)d_in[7];
  const float* Wo   = (const float*)d_in[8];
  const float* bo   = (const float*)d_in[9];
  float* out = (float*)d_out;

  char* wsb = (char*)d_ws;
  short* qb    = (short*)(wsb + 0);
  short* kb    = (short*)(wsb + 33554432);
  short* vT    = (short*)(wsb + 67108864);
  short* xb    = (short*)(wsb + 100663296);
  short* Wqkvb = (short*)(wsb + 134217728);
  short* Wob   = (short*)(wsb + 140509184);
  short* projT = (short*)(wsb + 142606336);
  float* kv_part = (float*)(wsb + 100663296);  // 32MB, overlays xb (dead after K1)
  short* attnb = kb;                            // kb dead after K2
  short* kvT   = vT;                            // vT dead after K2

  conv_all_kernel<<<dim3(20481), dim3(256), 0, stream>>>(
      x, Wq, Wk, Wv, Wo, proj, xb, Wqkvb, Wob, projT);

  qkv_gemm256_kernel<<<dim3(64, 12), dim3(512), 0, stream>>>(
      xb, Wqkvb, bq, bk, bv, qb, kb, vT);
  kv_accum_kernel<<<dim3(512), dim3(256), 0, stream>>>(kb, vT, projT, kv_part);
  kvT_kernel<<<dim3(64, 4), dim3(256), 0, stream>>>(kv_part, kvT);
  attn_kernel<<<dim3(256, 16), dim3(256), 0, stream>>>(qb, projT, kvT, attnb);
  out_gemm_kernel<<<dim3(128, 8), dim3(256), 0, stream>>>(attnb, Wob, bo, out);
}

// Round 4
// 396.442 us; speedup vs baseline: 1.1227x; 1.0538x over previous
//
#include <hip/hip_runtime.h>
#include <cstddef>
#include <cstdint>

// LinearAttention — bf16 MFMA. B=4 L=4096 D=1024 H=16 d=64 M=128 (2M=256).
// K0 fused convert -> K1 fused QKV GEMM (256^2 8-phase, Gray-code register
// reuse, counted vmcnt) -> K2 fourier(k)+kv outer (private partials)
// -> K2.5 reduce+transpose -> K3 fourier(q)+attn (LDS-staged kvT) -> K4 out GEMM.
//
// ws layout (bytes):
//   qb     @ 0          33.55MB  bf16 [16384][1024]
//   kb     @ 33554432   33.55MB  bf16 [16384][1024]   (reused as attnb)
//   vT     @ 67108864   33.55MB  bf16 [(b*16+h)*64+d][4096]  (reused as kvT)
//   xb     @ 100663296  33.55MB  bf16 [16384][1024]   (kv_part f32 32MB overlays after K1)
//   Wqkvb  @ 134217728   6.29MB  bf16 [3072][1024]
//   Wob    @ 140509184   2.10MB  bf16 [1024][1024]
//   projT  @ 142606336   16KB    bf16 [128 m][64 d]

typedef __attribute__((ext_vector_type(8))) short s8v;   // 8 x bf16 (16B)
typedef __attribute__((ext_vector_type(4))) short s4v;   // 4 x bf16 (8B)
typedef __attribute__((ext_vector_type(4))) float f32x4; // MFMA acc

#define MFMA_BF16(a, b, c) __builtin_amdgcn_mfma_f32_16x16x32_bf16((a), (b), (c), 0, 0, 0)

#define P_SCALE 0.125f                 // 1/sqrt(64)
#define F_SCALE 0.08838834764831845f   // 1/sqrt(128)

static __device__ __forceinline__ unsigned short f2bf(float f) {
  unsigned int u = __float_as_uint(f);
  u += 0x7fffu + ((u >> 16) & 1u);  // RNE
  return (unsigned short)(u >> 16);
}

// async 16B global->LDS (DMA; LDS dest = wave-uniform base + lane*16)
static __device__ __forceinline__ void gload_lds16(const void* g, void* l) {
  __builtin_amdgcn_global_load_lds(
      (const __attribute__((address_space(1))) unsigned int*)g,
      (__attribute__((address_space(3))) unsigned int*)l, 16, 0, 0);
}

// ---------------------------------------------------------------------------
// K0: fused fp32->bf16 convert for x (16M), Wq/Wk/Wv/Wo (1M each), projT.
// ---------------------------------------------------------------------------
__global__ void conv_all_kernel(const float* __restrict__ x,
                                const float* __restrict__ Wq, const float* __restrict__ Wk,
                                const float* __restrict__ Wv, const float* __restrict__ Wo,
                                const float* __restrict__ proj,
                                short* __restrict__ xb, short* __restrict__ Wqkvb,
                                short* __restrict__ Wob, short* __restrict__ projT) {
  const int bid = blockIdx.x;
  const int t = threadIdx.x;
  if (bid < 16384) {
    int i4 = (bid * 256 + t) * 4;
    float4 f = *(const float4*)(x + i4);
    s4v v;
    v[0] = (short)f2bf(f.x); v[1] = (short)f2bf(f.y);
    v[2] = (short)f2bf(f.z); v[3] = (short)f2bf(f.w);
    *(s4v*)(xb + i4) = v;
  } else if (bid < 20480) {
    int wi = (bid - 16384) >> 10;
    int lb = (bid - 16384) & 1023;
    const float* src = (wi == 0) ? Wq : (wi == 1) ? Wk : (wi == 2) ? Wv : Wo;
    short* dst = (wi < 3) ? (Wqkvb + (size_t)wi * 1048576) : Wob;
    int i4 = (lb * 256 + t) * 4;
    float4 f = *(const float4*)(src + i4);
    s4v v;
    v[0] = (short)f2bf(f.x); v[1] = (short)f2bf(f.y);
    v[2] = (short)f2bf(f.z); v[3] = (short)f2bf(f.w);
    *(s4v*)(dst + i4) = v;
  } else {
#pragma unroll
    for (int i = 0; i < 32; ++i) {
      int idx = t + i * 256;
      int d = idx >> 7, m = idx & 127;
      projT[m * 64 + d] = (short)f2bf(proj[idx]);
    }
  }
}

// ---------------------------------------------------------------------------
// K1: qkv = xb @ Wqkv^T + bias. 256x256 tile, BK=64, 8-phase (4 phases/tile),
// Gray-code quadrant walk (00->01->11->10) with persistent operand registers:
//   ph0: load A0+B0 (12 ds_read), ph1: load B1 (4), ph2: load A1 (8),
//   ph3: ZERO loads (reuses A1 regs + saved B0 regs). 24 ds_read/tile.
// Stage order A0',B0',B1',A1'; counted vmcnt(4) at ph0/ph1/ph3 (none ph2).
// grid (64 row-tiles, 12 col-tiles), 512 threads. bn 0-3: q, 4-7: k, 8-11: v.
// LDS: 2 dbuf x (A[2 half][128][64] + B[2 half][128][64]) = 128 KiB.
// ---------------------------------------------------------------------------
__global__ __launch_bounds__(512, 2) void qkv_gemm256_kernel(
    const short* __restrict__ xb, const short* __restrict__ Wqkv,
    const float* __restrict__ bq_, const float* __restrict__ bk_,
    const float* __restrict__ bv_,
    short* __restrict__ qb, short* __restrict__ kb, short* __restrict__ vT) {
  __shared__ __align__(16) short sm[65536];  // 128 KiB

  const int t = threadIdx.x;
  const int bm = blockIdx.x, bn = blockIdx.y;
  const int row0 = bm * 256, n0 = bn * 256;
  const int lane = t & 63, w = t >> 6;
  const int wr = w >> 2, wc = w & 3;
  const int l15 = lane & 15, lq = lane >> 4;
  const int sx = (l15 & 7) * 8;

  f32x4 acc[4][4][2];
#pragma unroll
  for (int q = 0; q < 4; ++q)
#pragma unroll
    for (int i = 0; i < 4; ++i)
#pragma unroll
      for (int j = 0; j < 2; ++j) acc[q][i][j] = (f32x4){0.f, 0.f, 0.f, 0.f};

  s8v af[4][2], bfr0[2][2], bfr1[2][2];  // persistent operand regs

#define STAGE_A(mh, k0v, pp) {                                                  \
    short* dsth = sm + (pp) * 32768 + (mh) * 8192;                              \
    _Pragma("unroll") for (int ii = 0; ii < 2; ++ii) {                          \
      int c = t + ii * 512; int r = c >> 3, cl = c & 7, cg = cl ^ (r & 7);      \
      gload_lds16(xb + (size_t)(row0 + (mh) * 128 + r) * 1024 + (k0v) + cg * 8, \
                  dsth + c * 8);                                                \
    } }
#define STAGE_B(nh, k0v, pp) {                                                  \
    short* dsth = sm + (pp) * 32768 + 16384 + (nh) * 8192;                      \
    _Pragma("unroll") for (int ii = 0; ii < 2; ++ii) {                          \
      int c = t + ii * 512; int r = c >> 3, cl = c & 7, cg = cl ^ (r & 7);      \
      gload_lds16(Wqkv + (size_t)(n0 + (nh) * 128 + r) * 1024 + (k0v) + cg * 8, \
                  dsth + c * 8);                                                \
    } }
#define VM4 asm volatile("s_waitcnt vmcnt(4)" ::: "memory")
#define VM0 asm volatile("s_waitcnt vmcnt(0)" ::: "memory")
#define LGKM0 asm volatile("s_waitcnt lgkmcnt(0)" ::: "memory")
#define BAR __builtin_amdgcn_s_barrier()

#define LD_A(mh) {                                                              \
    const short* Ah = sm + p * 32768 + (mh) * 8192;                             \
    _Pragma("unroll") for (int i = 0; i < 4; ++i)                               \
      _Pragma("unroll") for (int ks = 0; ks < 2; ++ks)                          \
        af[i][ks] = *(const s8v*)&Ah[(wr * 64 + i * 16 + l15) * 64 +            \
                                     (((ks * 4 + lq) * 8) ^ sx)];               \
  }
#define LD_B(dst, nh) {                                                         \
    const short* Bh = sm + p * 32768 + 16384 + (nh) * 8192;                     \
    _Pragma("unroll") for (int j = 0; j < 2; ++j)                               \
      _Pragma("unroll") for (int ks = 0; ks < 2; ++ks)                          \
        dst[j][ks] = *(const s8v*)&Bh[(wc * 32 + j * 16 + l15) * 64 +           \
                                      (((ks * 4 + lq) * 8) ^ sx)];              \
  }
#define MFMA_Q(q, bsrc) {                                                       \
    __builtin_amdgcn_s_setprio(1);                                              \
    _Pragma("unroll") for (int ks = 0; ks < 2; ++ks)                            \
      _Pragma("unroll") for (int i = 0; i < 4; ++i)                             \
        _Pragma("unroll") for (int j = 0; j < 2; ++j)                           \
          acc[q][i][j] = MFMA_BF16(af[i][ks], bsrc[j][ks], acc[q][i][j]);       \
    __builtin_amdgcn_s_setprio(0);                                              \
  }

  // prologue: stage K-tile 0 (A0,B0,B1,A1); VM4 leaves B1,A1 in flight
  STAGE_A(0, 0, 0);
  STAGE_B(0, 0, 0);
  STAGE_B(1, 0, 0);
  STAGE_A(1, 0, 0);
  VM4;
  BAR;

  int p = 0;
  for (int tt = 0; tt < 15; ++tt) {
    const int k1 = (tt + 1) * 64;
    // ph0: quadrant (0,0) — load A0,B0; stage A0'
    LD_A(0); LD_B(bfr0, 0);
    STAGE_A(0, k1, p ^ 1);
    VM4; BAR; LGKM0;
    MFMA_Q(0, bfr0);
    BAR;
    // ph1: quadrant (0,1) — load B1 (A0 kept); stage B0'
    LD_B(bfr1, 1);
    STAGE_B(0, k1, p ^ 1);
    VM4; BAR; LGKM0;
    MFMA_Q(1, bfr1);
    BAR;
    // ph2: quadrant (1,1) — load A1 (B1 kept); stage B1'
    LD_A(1);
    STAGE_B(1, k1, p ^ 1);
    BAR; LGKM0;
    MFMA_Q(3, bfr1);
    BAR;
    // ph3: quadrant (1,0) — ZERO loads (A1 kept, B0 saved); stage A1'
    STAGE_A(1, k1, p ^ 1);
    VM4; BAR;
    MFMA_Q(2, bfr0);
    BAR;
    p ^= 1;
  }
  // K-tile 15: drain once, compute barrier-free
  VM0;
  BAR;
  LD_A(0); LD_B(bfr0, 0); LGKM0;
  MFMA_Q(0, bfr0);
  LD_B(bfr1, 1); LGKM0;
  MFMA_Q(1, bfr1);
  LD_A(1); LGKM0;
  MFMA_Q(3, bfr1);
  MFMA_Q(2, bfr0);

  // -------- epilogue --------
  BAR;
  short* im = sm;  // image [128][264] (q/k: rows x cols; v: cols x rows)
  const int region = bn >> 2;  // 0 q, 1 k, 2 v
  if (region < 2) {
    const float* bias = (region == 0) ? bq_ : bk_;
    short* dst = (region == 0) ? qb : kb;
    const int cb = (bn & 3) * 256;
#pragma unroll
    for (int mh = 0; mh < 2; ++mh) {
#pragma unroll
      for (int nh = 0; nh < 2; ++nh)
#pragma unroll
        for (int j = 0; j < 2; ++j) {
          int cl = nh * 128 + wc * 32 + j * 16 + l15;
          float bsv = bias[cb + cl];
#pragma unroll
          for (int i = 0; i < 4; ++i)
#pragma unroll
            for (int r = 0; r < 4; ++r)
              im[(wr * 64 + i * 16 + lq * 4 + r) * 264 + cl] =
                  (short)f2bf(acc[mh * 2 + nh][i][j][r] + bsv);
        }
      BAR;
#pragma unroll
      for (int i = 0; i < 8; ++i) {
        int c = t + i * 512;
        int r = c >> 5, cc = c & 31;
        *(s8v*)&dst[(size_t)(row0 + mh * 128 + r) * 1024 + cb + cc * 8] =
            *(s8v*)&im[r * 264 + cc * 8];
      }
      BAR;
    }
  } else {
    const int b = bm >> 4;
    const int l0 = (bm & 15) * 256;
#pragma unroll
    for (int nh = 0; nh < 2; ++nh) {
#pragma unroll
      for (int mh = 0; mh < 2; ++mh)
#pragma unroll
        for (int j = 0; j < 2; ++j) {
          int cl = wc * 32 + j * 16 + l15;  // 0..127 within nh
          float bsv = bv_[(bn - 8) * 256 + nh * 128 + cl];
#pragma unroll
          for (int i = 0; i < 4; ++i) {
            s4v pk;
#pragma unroll
            for (int r = 0; r < 4; ++r)
              pk[r] = (short)f2bf(acc[mh * 2 + nh][i][j][r] + bsv);
            *(s4v*)&im[cl * 264 + mh * 128 + wr * 64 + i * 16 + lq * 4] = pk;
          }
        }
      BAR;
#pragma unroll
      for (int i = 0; i < 8; ++i) {
        int c = t + i * 512;
        int cp = c >> 5, rr8 = (c & 31) * 8;
        int cv = (bn - 8) * 256 + nh * 128 + cp;
        int grow = (b * 16 + (cv >> 6)) * 64 + (cv & 63);
        *(s8v*)&vT[(size_t)grow * 4096 + l0 + rr8] = *(s8v*)&im[cp * 264 + rr8];
      }
      BAR;
    }
  }
#undef STAGE_A
#undef STAGE_B
#undef VM4
#undef VM0
#undef LGKM0
#undef BAR
#undef LD_A
#undef LD_B
#undef MFMA_Q
}

// ---------------------------------------------------------------------------
// K2: per (b,h,512-row chunk): fourier(k) -> k' ; kv_part[chunk] = k'^T @ v
// (MFMA, PRIVATE per-block output — no atomics). grid 512.
// kv_part layout: [chunk 8][bh 64][m 256][d 64] f32 (32MB, overlays dead xb).
// ---------------------------------------------------------------------------
__global__ void kv_accum_kernel(const short* __restrict__ kb, const short* __restrict__ vT,
                                const short* __restrict__ projT, float* __restrict__ kv) {
  __shared__ __align__(16) short smem[26624];  // kt[64][64]+vt[64][64]+kpT[256][72]
  short* kt = smem;
  short* vt = smem + 4096;
  short* kpT = smem + 8192;

  const int t = threadIdx.x;
  const int bid = blockIdx.x;
  const int chunk = bid & 7, h = (bid >> 3) & 15, b = bid >> 7;
  const int lane = t & 63, w = t >> 6;
  const int l15 = lane & 15, lq = lane >> 4;
  const int sx = (l15 & 7) * 8;

  s8v pf[8][2];
#pragma unroll
  for (int nt = 0; nt < 8; ++nt)
#pragma unroll
    for (int ks = 0; ks < 2; ++ks)
      pf[nt][ks] = *(const s8v*)(projT + (size_t)(nt * 16 + l15) * 64 + ks * 32 + lq * 8);

  f32x4 kvacc[4][4];
#pragma unroll
  for (int i = 0; i < 4; ++i)
#pragma unroll
    for (int j = 0; j < 4; ++j) kvacc[i][j] = (f32x4){0.f, 0.f, 0.f, 0.f};

  for (int s = 0; s < 8; ++s) {
    const int l0s = chunk * 512 + s * 64;
#pragma unroll
    for (int i = 0; i < 2; ++i) {
      int c = t + i * 256;                 // chunk 0..511
      int r = c >> 3, cl = c & 7;
      int cg = cl ^ (r & 7);
      gload_lds16(kb + (size_t)(b * 4096 + l0s + r) * 1024 + h * 64 + cg * 8, kt + c * 8);
      gload_lds16(vT + (size_t)((b * 16 + h) * 64 + r) * 4096 + l0s + cg * 8, vt + c * 8);
    }
    __syncthreads();

    // fourier: wave w rows w*16..+15
    f32x4 pacc[8];
#pragma unroll
    for (int nt = 0; nt < 8; ++nt) pacc[nt] = (f32x4){0.f, 0.f, 0.f, 0.f};
#pragma unroll
    for (int ks = 0; ks < 2; ++ks) {
      const int kb8 = (ks * 4 + lq) * 8;
      s8v af = *(s8v*)&kt[(w * 16 + l15) * 64 + (kb8 ^ sx)];
#pragma unroll
      for (int nt = 0; nt < 8; ++nt) pacc[nt] = MFMA_BF16(af, pf[nt][ks], pacc[nt]);
    }
#pragma unroll
    for (int nt = 0; nt < 8; ++nt) {
      s4v cp, sp;
#pragma unroll
      for (int r = 0; r < 4; ++r) {
        float pv = pacc[nt][r] * P_SCALE;
        float sv, cv;
        __sincosf(pv, &sv, &cv);
        cp[r] = (short)f2bf(cv * F_SCALE);
        sp[r] = (short)f2bf(sv * F_SCALE);
      }
      int m = nt * 16 + l15;
      int rbase = w * 16 + lq * 4;
      *(s4v*)&kpT[m * 72 + rbase] = cp;
      *(s4v*)&kpT[(m + 128) * 72 + rbase] = sp;
    }
    __syncthreads();

    // kv MFMA: wave w m-range w*64..+63
#pragma unroll
    for (int ks = 0; ks < 2; ++ks) {
      const int kb8 = (ks * 4 + lq) * 8;
      s8v af[4], bf4[4];
#pragma unroll
      for (int i = 0; i < 4; ++i)
        af[i] = *(s8v*)&kpT[(w * 64 + i * 16 + l15) * 72 + ks * 32 + lq * 8];
#pragma unroll
      for (int j = 0; j < 4; ++j)
        bf4[j] = *(s8v*)&vt[(j * 16 + l15) * 64 + (kb8 ^ sx)];
#pragma unroll
      for (int i = 0; i < 4; ++i)
#pragma unroll
        for (int j = 0; j < 4; ++j)
          kvacc[i][j] = MFMA_BF16(af[i], bf4[j], kvacc[i][j]);
    }
    __syncthreads();
  }

  // private partial: kv_part[chunk][bh][m][d], plain coalesced stores
  float* kvb = kv + (size_t)chunk * 1048576 + ((size_t)(b * 16 + h) << 14);
#pragma unroll
  for (int i = 0; i < 4; ++i)
#pragma unroll
    for (int j = 0; j < 4; ++j)
#pragma unroll
      for (int r = 0; r < 4; ++r) {
        int m = w * 64 + i * 16 + lq * 4 + r;
        int d = j * 16 + l15;
        kvb[(size_t)m * 64 + d] = kvacc[i][j][r];
      }
}

// ---------------------------------------------------------------------------
// K2.5: reduce 8 kv partials f32 -> kvT bf16 [bh*64+d][256]. grid (64,4).
// ---------------------------------------------------------------------------
__global__ void kvT_kernel(const float* __restrict__ kvp, short* __restrict__ kvT) {
  __shared__ __align__(16) short im[4608];  // [64 d][72]
  const int t = threadIdx.x;
  const int bh = blockIdx.x, mc = blockIdx.y;
  const float* base = kvp + (size_t)bh * 16384 + (size_t)mc * 4096;
#pragma unroll
  for (int i = 0; i < 4; ++i) {
    int idx4 = t + i * 256;                // 1024 float4s = [64 m][64 d]
    int mm = idx4 >> 4, d4 = (idx4 & 15) * 4;
    float4 s = {0.f, 0.f, 0.f, 0.f};
#pragma unroll
    for (int c = 0; c < 8; ++c) {
      float4 v = *(const float4*)(base + (size_t)c * 1048576 + mm * 64 + d4);
      s.x += v.x; s.y += v.y; s.z += v.z; s.w += v.w;
    }
    im[(d4 + 0) * 72 + mm] = (short)f2bf(s.x);
    im[(d4 + 1) * 72 + mm] = (short)f2bf(s.y);
    im[(d4 + 2) * 72 + mm] = (short)f2bf(s.z);
    im[(d4 + 3) * 72 + mm] = (short)f2bf(s.w);
  }
  __syncthreads();
#pragma unroll
  for (int i = 0; i < 2; ++i) {
    int c = t + i * 256;                   // 512 stores x 16B = [64 d][64 m]
    int d = c >> 3, mm8 = (c & 7) * 8;
    *(s8v*)&kvT[(size_t)(bh * 64 + d) * 256 + mc * 64 + mm8] = *(s8v*)&im[d * 72 + mm8];
  }
}

// ---------------------------------------------------------------------------
// K3: fourier(q) + attn = q' @ kv, per (64-row tile, head). grid (256,16).
// kvT staged via global_load_lds (XOR-swizzled).
// ---------------------------------------------------------------------------
__global__ void attn_kernel(const short* __restrict__ qb, const short* __restrict__ projT,
                            const short* __restrict__ kvT, short* __restrict__ attnb) {
  __shared__ __align__(16) short smem[20992];  // qt[64][64]+qA[64][136]+kvt[64][128]
  short* qt = smem;
  short* qA = smem + 4096;
  short* kvt = smem + 12800;

  const int t = threadIdx.x;
  const int rt = blockIdx.x, h = blockIdx.y;
  const int row0 = rt * 64;
  const int b = row0 >> 12;
  const int lane = t & 63, w = t >> 6;
  const int l15 = lane & 15, lq = lane >> 4;
  const int sx = (l15 & 7) * 8;

  s8v pf[8][2];
#pragma unroll
  for (int nt = 0; nt < 8; ++nt)
#pragma unroll
    for (int ks = 0; ks < 2; ++ks)
      pf[nt][ks] = *(const s8v*)(projT + (size_t)(nt * 16 + l15) * 64 + ks * 32 + lq * 8);

#pragma unroll
  for (int i = 0; i < 2; ++i) {
    int c = t + i * 256;
    int r = c >> 3, cl = c & 7;
    int cg = cl ^ (r & 7);
    gload_lds16(qb + (size_t)(row0 + r) * 1024 + h * 64 + cg * 8, qt + c * 8);
  }
  __syncthreads();

  f32x4 pacc[8];
#pragma unroll
  for (int nt = 0; nt < 8; ++nt) pacc[nt] = (f32x4){0.f, 0.f, 0.f, 0.f};
#pragma unroll
  for (int ks = 0; ks < 2; ++ks) {
    const int kb8 = (ks * 4 + lq) * 8;
    s8v af = *(s8v*)&qt[(w * 16 + l15) * 64 + (kb8 ^ sx)];
#pragma unroll
    for (int nt = 0; nt < 8; ++nt) pacc[nt] = MFMA_BF16(af, pf[nt][ks], pacc[nt]);
  }

  f32x4 aacc[4];
#pragma unroll
  for (int j = 0; j < 4; ++j) aacc[j] = (f32x4){0.f, 0.f, 0.f, 0.f};

#pragma unroll
  for (int half = 0; half < 2; ++half) {
    // q' half -> qA [64][136]
#pragma unroll
    for (int nt = 0; nt < 8; ++nt)
#pragma unroll
      for (int r = 0; r < 4; ++r) {
        float p = pacc[nt][r] * P_SCALE;
        float fv = (half == 0) ? __cosf(p) : __sinf(p);
        qA[(w * 16 + lq * 4 + r) * 136 + nt * 16 + l15] = (short)f2bf(fv * F_SCALE);
      }
    // stage kvT half: [64 d][128 m'], swizzled (16 chunks/row)
#pragma unroll
    for (int i = 0; i < 4; ++i) {
      int c = t + i * 256;                 // chunk 0..1023
      int d = c >> 4, cl = c & 15;
      int cg = cl ^ (d & 15);
      gload_lds16(kvT + (size_t)((b * 16 + h) * 64 + d) * 256 + half * 128 + cg * 8,
                  kvt + c * 8);
    }
    __syncthreads();
#pragma unroll
    for (int ks = 0; ks < 4; ++ks) {
      s8v af = *(s8v*)&qA[(w * 16 + l15) * 136 + ks * 32 + lq * 8];
#pragma unroll
      for (int j = 0; j < 4; ++j) {
        int row = j * 16 + l15;
        s8v bf4 = *(s8v*)&kvt[row * 128 + (((ks * 4 + lq) ^ l15) * 8)];
        aacc[j] = MFMA_BF16(af, bf4, aacc[j]);
      }
    }
    __syncthreads();
  }

  // epilogue image at smem base [64][72]
#pragma unroll
  for (int j = 0; j < 4; ++j)
#pragma unroll
    for (int r = 0; r < 4; ++r)
      smem[(w * 16 + lq * 4 + r) * 72 + j * 16 + l15] = (short)f2bf(aacc[j][r]);
  __syncthreads();
#pragma unroll
  for (int i = 0; i < 2; ++i) {
    int c = t + i * 256;
    int r = c >> 3, cc = c & 7;
    *(s8v*)&attnb[(size_t)(row0 + r) * 1024 + h * 64 + cc * 8] = *(s8v*)&smem[r * 72 + cc * 8];
  }
}

// ---------------------------------------------------------------------------
// K4: out = attn @ Wo^T + bo. fp32 out. grid (128, 8).
// ---------------------------------------------------------------------------
__global__ void out_gemm_kernel(const short* __restrict__ attnb, const short* __restrict__ Wob,
                                const float* __restrict__ bo_, float* __restrict__ out) {
  __shared__ __align__(16) short smem[16384];
  short* Al = smem;
  short* Bl = smem + 8192;

  const int t = threadIdx.x;
  const int bm = blockIdx.x, bn = blockIdx.y;
  const int row0 = bm * 128, n0 = bn * 128;
  const int lane = t & 63, w = t >> 6;
  const int wm = w & 1, wn = w >> 1;
  const int l15 = lane & 15, lq = lane >> 4;
  const int sx = (l15 & 7) * 8;

  f32x4 acc[4][4];
#pragma unroll
  for (int i = 0; i < 4; ++i)
#pragma unroll
    for (int j = 0; j < 4; ++j) acc[i][j] = (f32x4){0.f, 0.f, 0.f, 0.f};

  for (int k0 = 0; k0 < 1024; k0 += 64) {
#pragma unroll
    for (int i = 0; i < 4; ++i) {
      int c = t + i * 256;
      int r = c >> 3, cl = c & 7;
      int cg = cl ^ (r & 7);
      gload_lds16(attnb + (size_t)(row0 + r) * 1024 + k0 + cg * 8, Al + c * 8);
      gload_lds16(Wob   + (size_t)(n0 + r) * 1024 + k0 + cg * 8, Bl + c * 8);
    }
    __syncthreads();
#pragma unroll
    for (int ks = 0; ks < 2; ++ks) {
      const int kb8 = (ks * 4 + lq) * 8;
      s8v af[4], bfr[4];
#pragma unroll
      for (int i = 0; i < 4; ++i)
        af[i] = *(s8v*)&Al[(wm * 64 + i * 16 + l15) * 64 + (kb8 ^ sx)];
#pragma unroll
      for (int j = 0; j < 4; ++j)
        bfr[j] = *(s8v*)&Bl[(wn * 64 + j * 16 + l15) * 64 + (kb8 ^ sx)];
#pragma unroll
      for (int i = 0; i < 4; ++i)
#pragma unroll
        for (int j = 0; j < 4; ++j)
          acc[i][j] = MFMA_BF16(af[i], bfr[j], acc[i][j]);
    }
    __syncthreads();
  }

#pragma unroll
  for (int j = 0; j < 4; ++j) {
    int cl = wn * 64 + j * 16 + l15;
    float bsv = bo_[n0 + cl];
#pragma unroll
    for (int i = 0; i < 4; ++i)
#pragma unroll
      for (int r = 0; r < 4; ++r)
        out[(size_t)(row0 + wm * 64 + i * 16 + lq * 4 + r) * 1024 + n0 + cl] =
            acc[i][j][r] + bsv;
  }
}

// ---------------------------------------------------------------------------
extern "C" void kernel_launch(void* const* d_in, const int* in_sizes, int n_in,
                              void* d_out, int out_size, void* d_ws, size_t ws_size,
                              hipStream_t stream) {
  const float* x    = (const float*)d_in[0];
  const float* proj = (const float*)d_in[1];
  const float* Wq   = (const float*)d_in[2];
  const float* bq   = (const float*)d_in[3];
  const float* Wk   = (const float*)d_in[4];
  const float* bk   = (const float*)d_in[5];
  const float* Wv   = (const float*)d_in[6];
  const float* bv   = (const float*)d_in[7];
  const float* Wo   = (const float*)d_in[8];
  const float* bo   = (const float*)d_in[9];
  float* out = (float*)d_out;

  char* wsb = (char*)d_ws;
  short* qb    = (short*)(wsb + 0);
  short* kb    = (short*)(wsb + 33554432);
  short* vT    = (short*)(wsb + 67108864);
  short* xb    = (short*)(wsb + 100663296);
  short* Wqkvb = (short*)(wsb + 134217728);
  short* Wob   = (short*)(wsb + 140509184);
  short* projT = (short*)(wsb + 142606336);
  float* kv_part = (float*)(wsb + 100663296);  // 32MB, overlays xb (dead after K1)
  short* attnb = kb;                            // kb dead after K2
  short* kvT   = vT;                            // vT dead after K2

  conv_all_kernel<<<dim3(20481), dim3(256), 0, stream>>>(
      x, Wq, Wk, Wv, Wo, proj, xb, Wqkvb, Wob, projT);

  qkv_gemm256_kernel<<<dim3(64, 12), dim3(512), 0, stream>>>(
      xb, Wqkvb, bq, bk, bv, qb, kb, vT);
  kv_accum_kernel<<<dim3(512), dim3(256), 0, stream>>>(kb, vT, projT, kv_part);
  kvT_kernel<<<dim3(64, 4), dim3(256), 0, stream>>>(kv_part, kvT);
  attn_kernel<<<dim3(256, 16), dim3(256), 0, stream>>>(qb, projT, kvT, attnb);
  out_gemm_kernel<<<dim3(128, 8), dim3(256), 0, stream>>>(attnb, Wob, bo, out);
}

// Round 5
// 393.289 us; speedup vs baseline: 1.1317x; 1.0080x over previous
//
#include <hip/hip_runtime.h>
#include <cstddef>
#include <cstdint>

// LinearAttention — bf16 MFMA, global_load_lds staging, XOR-swizzled LDS.
// B=4 L=4096 D=1024 H=16 d=64 M=128 (2M=256).
// K0 fused convert (grid-stride, 2048 blocks) -> K1 fused QKV GEMM (128^2,
// proven) -> K2 fourier(k)+kv outer (private partials) -> K2.5 reduce+transpose
// -> K3 fourier(q)+attn (LDS-staged kvT) -> K4 out GEMM.
//
// ws layout (bytes):
//   qb     @ 0          33.55MB  bf16 [16384][1024]
//   kb     @ 33554432   33.55MB  bf16 [16384][1024]   (reused as attnb)
//   vT     @ 67108864   33.55MB  bf16 [(b*16+h)*64+d][4096]  (reused as kvT)
//   xb     @ 100663296  33.55MB  bf16 [16384][1024]   (kv_part f32 32MB overlays after K1)
//   Wqkvb  @ 134217728   6.29MB  bf16 [3072][1024]
//   Wob    @ 140509184   2.10MB  bf16 [1024][1024]
//   projT  @ 142606336   16KB    bf16 [128 m][64 d]

typedef __attribute__((ext_vector_type(8))) short s8v;   // 8 x bf16 (16B)
typedef __attribute__((ext_vector_type(4))) short s4v;   // 4 x bf16 (8B)
typedef __attribute__((ext_vector_type(4))) float f32x4; // MFMA acc

#define MFMA_BF16(a, b, c) __builtin_amdgcn_mfma_f32_16x16x32_bf16((a), (b), (c), 0, 0, 0)

#define P_SCALE 0.125f                 // 1/sqrt(64)
#define F_SCALE 0.08838834764831845f   // 1/sqrt(128)

static __device__ __forceinline__ unsigned short f2bf(float f) {
  unsigned int u = __float_as_uint(f);
  u += 0x7fffu + ((u >> 16) & 1u);  // RNE
  return (unsigned short)(u >> 16);
}

// async 16B global->LDS (DMA; LDS dest = wave-uniform base + lane*16)
static __device__ __forceinline__ void gload_lds16(const void* g, void* l) {
  __builtin_amdgcn_global_load_lds(
      (const __attribute__((address_space(1))) unsigned int*)g,
      (__attribute__((address_space(3))) unsigned int*)l, 16, 0, 0);
}

// ---------------------------------------------------------------------------
// K0: fused fp32->bf16 convert, GRID-STRIDE (2048 blocks x 256 thr).
// flat float4 index space: [0,4194304) x; [4194304,5242880) Wq/Wk/Wv/Wo;
// [5242880,5244928) proj (transposed to projT).
// 20481-block version was dispatch-bound (~3ns/block ~ 60us for ~20us of BW).
// ---------------------------------------------------------------------------
__global__ void conv_all_kernel(const float* __restrict__ x,
                                const float* __restrict__ Wq, const float* __restrict__ Wk,
                                const float* __restrict__ Wv, const float* __restrict__ Wo,
                                const float* __restrict__ proj,
                                short* __restrict__ xb, short* __restrict__ Wqkvb,
                                short* __restrict__ Wob, short* __restrict__ projT) {
  const int T = blockIdx.x * 256 + threadIdx.x;  // 0..524287
  for (int u = T; u < 5244928; u += 524288) {
    if (u < 4194304) {
      float4 f = ((const float4*)x)[u];
      s4v v;
      v[0] = (short)f2bf(f.x); v[1] = (short)f2bf(f.y);
      v[2] = (short)f2bf(f.z); v[3] = (short)f2bf(f.w);
      ((s4v*)xb)[u] = v;
    } else if (u < 5242880) {
      int vi = u - 4194304;
      int wi = vi >> 18;           // 0..3 (Wq,Wk,Wv,Wo), 262144 float4 each
      int off = vi & 262143;
      const float* src = (wi == 0) ? Wq : (wi == 1) ? Wk : (wi == 2) ? Wv : Wo;
      short* dst = (wi < 3) ? (Wqkvb + (size_t)wi * 1048576) : Wob;
      float4 f = ((const float4*)src)[off];
      s4v v;
      v[0] = (short)f2bf(f.x); v[1] = (short)f2bf(f.y);
      v[2] = (short)f2bf(f.z); v[3] = (short)f2bf(f.w);
      ((s4v*)dst)[off] = v;
    } else {
      int vi = u - 5242880;        // proj [64 d][128 m]: 32 float4 per row
      int d = vi >> 5, m4 = (vi & 31) * 4;
      float4 f = ((const float4*)proj)[vi];
      projT[(m4 + 0) * 64 + d] = (short)f2bf(f.x);
      projT[(m4 + 1) * 64 + d] = (short)f2bf(f.y);
      projT[(m4 + 2) * 64 + d] = (short)f2bf(f.z);
      projT[(m4 + 3) * 64 + d] = (short)f2bf(f.w);
    }
  }
}

// ---------------------------------------------------------------------------
// K1: qkv = xb @ Wqkv^T + bias. 128x128 tile, BK=64, bf16 MFMA,
// global_load_lds staging with XOR chunk swizzle. (Proven: 103us, 45% MfmaUtil.
// 256^2 8-phase ports measured SLOWER: 138us naive, 110us Gray-code-reuse.)
// grid (128 row-tiles, 24 col-tiles). bn 0-7: q, 8-15: k, 16-23: v.
// ---------------------------------------------------------------------------
__global__ void qkv_gemm_kernel(const short* __restrict__ xb,
                                const short* __restrict__ Wqkv,
                                const float* __restrict__ bq_, const float* __restrict__ bk_,
                                const float* __restrict__ bv_,
                                short* __restrict__ qb, short* __restrict__ kb,
                                short* __restrict__ vT) {
  __shared__ __align__(16) short smem[17408];  // A[128][64]+B[128][64]; epi image [128][136]
  short* Al = smem;
  short* Bl = smem + 8192;

  const int t = threadIdx.x;
  const int bm = blockIdx.x, bn = blockIdx.y;
  const int row0 = bm * 128, n0 = bn * 128;
  const int lane = t & 63, w = t >> 6;
  const int wm = w & 1, wn = w >> 1;
  const int l15 = lane & 15, lq = lane >> 4;
  const int sx = (l15 & 7) * 8;   // fragment-read swizzle term (in shorts)

  f32x4 acc[4][4];
#pragma unroll
  for (int i = 0; i < 4; ++i)
#pragma unroll
    for (int j = 0; j < 4; ++j) acc[i][j] = (f32x4){0.f, 0.f, 0.f, 0.f};

  for (int k0 = 0; k0 < 1024; k0 += 64) {
#pragma unroll
    for (int i = 0; i < 4; ++i) {
      int c = t + i * 256;                 // chunk 0..1023
      int r = c >> 3, cl = c & 7;
      int cg = cl ^ (r & 7);               // permuted global chunk
      gload_lds16(xb   + (size_t)(row0 + r) * 1024 + k0 + cg * 8, Al + c * 8);
      gload_lds16(Wqkv + (size_t)(n0 + r) * 1024 + k0 + cg * 8, Bl + c * 8);
    }
    __syncthreads();
#pragma unroll
    for (int ks = 0; ks < 2; ++ks) {
      const int kb8 = (ks * 4 + lq) * 8;
      s8v af[4], bfr[4];
#pragma unroll
      for (int i = 0; i < 4; ++i)
        af[i] = *(s8v*)&Al[(wm * 64 + i * 16 + l15) * 64 + (kb8 ^ sx)];
#pragma unroll
      for (int j = 0; j < 4; ++j)
        bfr[j] = *(s8v*)&Bl[(wn * 64 + j * 16 + l15) * 64 + (kb8 ^ sx)];
#pragma unroll
      for (int i = 0; i < 4; ++i)
#pragma unroll
        for (int j = 0; j < 4; ++j)
          acc[i][j] = MFMA_BF16(af[i], bfr[j], acc[i][j]);
    }
    __syncthreads();
  }

  const int region = bn >> 3;  // 0 q, 1 k, 2 v
  if (region < 2) {
    const float* bias = (region == 0) ? bq_ : bk_;
    short* IM = smem;  // [128][136] natural image
#pragma unroll
    for (int j = 0; j < 4; ++j) {
      int cl = wn * 64 + j * 16 + l15;
      float bsv = bias[(n0 & 1023) + cl];
#pragma unroll
      for (int i = 0; i < 4; ++i)
#pragma unroll
        for (int r = 0; r < 4; ++r)
          IM[(wm * 64 + i * 16 + lq * 4 + r) * 136 + cl] = (short)f2bf(acc[i][j][r] + bsv);
    }
    __syncthreads();
    short* dst = (region == 0) ? qb : kb;
#pragma unroll
    for (int i = 0; i < 8; ++i) {
      int c = t + i * 256;
      int r = c >> 4, cc = c & 15;
      *(s8v*)&dst[(size_t)(row0 + r) * 1024 + (n0 & 1023) + cc * 8] =
          *(s8v*)&IM[r * 136 + cc * 8];
    }
  } else {
    short* IM = smem;  // [128 col][136] transposed image
#pragma unroll
    for (int j = 0; j < 4; ++j) {
      int cl = wn * 64 + j * 16 + l15;
      float bsv = bv_[(n0 - 2048) + cl];
#pragma unroll
      for (int i = 0; i < 4; ++i) {
        s4v pk;
#pragma unroll
        for (int r = 0; r < 4; ++r) pk[r] = (short)f2bf(acc[i][j][r] + bsv);
        *(s4v*)&IM[cl * 136 + wm * 64 + i * 16 + lq * 4] = pk;
      }
    }
    __syncthreads();
    const int b = row0 >> 12;
    const int l0 = (bm & 31) * 128;
#pragma unroll
    for (int i = 0; i < 8; ++i) {
      int c = t + i * 256;
      int ci = c >> 4, cc = c & 15;
      int cv = (bn - 16) * 128 + ci;      // 0..1023
      int grow = (b * 16 + (cv >> 6)) * 64 + (cv & 63);
      *(s8v*)&vT[(size_t)grow * 4096 + l0 + cc * 8] = *(s8v*)&IM[ci * 136 + cc * 8];
    }
  }
}

// ---------------------------------------------------------------------------
// K2: per (b,h,512-row chunk): fourier(k) -> k' ; kv_part[chunk] = k'^T @ v
// (MFMA, PRIVATE per-block output — no atomics). grid 512.
// kv_part layout: [chunk 8][bh 64][m 256][d 64] f32 (32MB, overlays dead xb).
// ---------------------------------------------------------------------------
__global__ void kv_accum_kernel(const short* __restrict__ kb, const short* __restrict__ vT,
                                const short* __restrict__ projT, float* __restrict__ kv) {
  __shared__ __align__(16) short smem[26624];  // kt[64][64]+vt[64][64]+kpT[256][72]
  short* kt = smem;
  short* vt = smem + 4096;
  short* kpT = smem + 8192;

  const int t = threadIdx.x;
  const int bid = blockIdx.x;
  const int chunk = bid & 7, h = (bid >> 3) & 15, b = bid >> 7;
  const int lane = t & 63, w = t >> 6;
  const int l15 = lane & 15, lq = lane >> 4;
  const int sx = (l15 & 7) * 8;

  s8v pf[8][2];
#pragma unroll
  for (int nt = 0; nt < 8; ++nt)
#pragma unroll
    for (int ks = 0; ks < 2; ++ks)
      pf[nt][ks] = *(const s8v*)(projT + (size_t)(nt * 16 + l15) * 64 + ks * 32 + lq * 8);

  f32x4 kvacc[4][4];
#pragma unroll
  for (int i = 0; i < 4; ++i)
#pragma unroll
    for (int j = 0; j < 4; ++j) kvacc[i][j] = (f32x4){0.f, 0.f, 0.f, 0.f};

  for (int s = 0; s < 8; ++s) {
    const int l0s = chunk * 512 + s * 64;
#pragma unroll
    for (int i = 0; i < 2; ++i) {
      int c = t + i * 256;                 // chunk 0..511
      int r = c >> 3, cl = c & 7;
      int cg = cl ^ (r & 7);
      gload_lds16(kb + (size_t)(b * 4096 + l0s + r) * 1024 + h * 64 + cg * 8, kt + c * 8);
      gload_lds16(vT + (size_t)((b * 16 + h) * 64 + r) * 4096 + l0s + cg * 8, vt + c * 8);
    }
    __syncthreads();

    // fourier: wave w rows w*16..+15
    f32x4 pacc[8];
#pragma unroll
    for (int nt = 0; nt < 8; ++nt) pacc[nt] = (f32x4){0.f, 0.f, 0.f, 0.f};
#pragma unroll
    for (int ks = 0; ks < 2; ++ks) {
      const int kb8 = (ks * 4 + lq) * 8;
      s8v af = *(s8v*)&kt[(w * 16 + l15) * 64 + (kb8 ^ sx)];
#pragma unroll
      for (int nt = 0; nt < 8; ++nt) pacc[nt] = MFMA_BF16(af, pf[nt][ks], pacc[nt]);
    }
#pragma unroll
    for (int nt = 0; nt < 8; ++nt) {
      s4v cp, sp;
#pragma unroll
      for (int r = 0; r < 4; ++r) {
        float pv = pacc[nt][r] * P_SCALE;
        float sv, cv;
        __sincosf(pv, &sv, &cv);
        cp[r] = (short)f2bf(cv * F_SCALE);
        sp[r] = (short)f2bf(sv * F_SCALE);
      }
      int m = nt * 16 + l15;
      int rbase = w * 16 + lq * 4;
      *(s4v*)&kpT[m * 72 + rbase] = cp;
      *(s4v*)&kpT[(m + 128) * 72 + rbase] = sp;
    }
    __syncthreads();

    // kv MFMA: wave w m-range w*64..+63
#pragma unroll
    for (int ks = 0; ks < 2; ++ks) {
      const int kb8 = (ks * 4 + lq) * 8;
      s8v af[4], bf4[4];
#pragma unroll
      for (int i = 0; i < 4; ++i)
        af[i] = *(s8v*)&kpT[(w * 64 + i * 16 + l15) * 72 + ks * 32 + lq * 8];
#pragma unroll
      for (int j = 0; j < 4; ++j)
        bf4[j] = *(s8v*)&vt[(j * 16 + l15) * 64 + (kb8 ^ sx)];
#pragma unroll
      for (int i = 0; i < 4; ++i)
#pragma unroll
        for (int j = 0; j < 4; ++j)
          kvacc[i][j] = MFMA_BF16(af[i], bf4[j], kvacc[i][j]);
    }
    __syncthreads();
  }

  // private partial: kv_part[chunk][bh][m][d], plain coalesced stores
  float* kvb = kv + (size_t)chunk * 1048576 + ((size_t)(b * 16 + h) << 14);
#pragma unroll
  for (int i = 0; i < 4; ++i)
#pragma unroll
    for (int j = 0; j < 4; ++j)
#pragma unroll
      for (int r = 0; r < 4; ++r) {
        int m = w * 64 + i * 16 + lq * 4 + r;
        int d = j * 16 + l15;
        kvb[(size_t)m * 64 + d] = kvacc[i][j][r];
      }
}

// ---------------------------------------------------------------------------
// K2.5: reduce 8 kv partials f32 -> kvT bf16 [bh*64+d][256]. grid (64,4).
// ---------------------------------------------------------------------------
__global__ void kvT_kernel(const float* __restrict__ kvp, short* __restrict__ kvT) {
  __shared__ __align__(16) short im[4608];  // [64 d][72]
  const int t = threadIdx.x;
  const int bh = blockIdx.x, mc = blockIdx.y;
  const float* base = kvp + (size_t)bh * 16384 + (size_t)mc * 4096;
#pragma unroll
  for (int i = 0; i < 4; ++i) {
    int idx4 = t + i * 256;                // 1024 float4s = [64 m][64 d]
    int mm = idx4 >> 4, d4 = (idx4 & 15) * 4;
    float4 s = {0.f, 0.f, 0.f, 0.f};
#pragma unroll
    for (int c = 0; c < 8; ++c) {
      float4 v = *(const float4*)(base + (size_t)c * 1048576 + mm * 64 + d4);
      s.x += v.x; s.y += v.y; s.z += v.z; s.w += v.w;
    }
    im[(d4 + 0) * 72 + mm] = (short)f2bf(s.x);
    im[(d4 + 1) * 72 + mm] = (short)f2bf(s.y);
    im[(d4 + 2) * 72 + mm] = (short)f2bf(s.z);
    im[(d4 + 3) * 72 + mm] = (short)f2bf(s.w);
  }
  __syncthreads();
#pragma unroll
  for (int i = 0; i < 2; ++i) {
    int c = t + i * 256;                   // 512 stores x 16B = [64 d][64 m]
    int d = c >> 3, mm8 = (c & 7) * 8;
    *(s8v*)&kvT[(size_t)(bh * 64 + d) * 256 + mc * 64 + mm8] = *(s8v*)&im[d * 72 + mm8];
  }
}

// ---------------------------------------------------------------------------
// K3: fourier(q) + attn = q' @ kv, per (64-row tile, head). grid (256,16).
// kvT staged via global_load_lds (XOR-swizzled).
// ---------------------------------------------------------------------------
__global__ void attn_kernel(const short* __restrict__ qb, const short* __restrict__ projT,
                            const short* __restrict__ kvT, short* __restrict__ attnb) {
  __shared__ __align__(16) short smem[20992];  // qt[64][64]+qA[64][136]+kvt[64][128]
  short* qt = smem;
  short* qA = smem + 4096;
  short* kvt = smem + 12800;

  const int t = threadIdx.x;
  const int rt = blockIdx.x, h = blockIdx.y;
  const int row0 = rt * 64;
  const int b = row0 >> 12;
  const int lane = t & 63, w = t >> 6;
  const int l15 = lane & 15, lq = lane >> 4;
  const int sx = (l15 & 7) * 8;

  s8v pf[8][2];
#pragma unroll
  for (int nt = 0; nt < 8; ++nt)
#pragma unroll
    for (int ks = 0; ks < 2; ++ks)
      pf[nt][ks] = *(const s8v*)(projT + (size_t)(nt * 16 + l15) * 64 + ks * 32 + lq * 8);

#pragma unroll
  for (int i = 0; i < 2; ++i) {
    int c = t + i * 256;
    int r = c >> 3, cl = c & 7;
    int cg = cl ^ (r & 7);
    gload_lds16(qb + (size_t)(row0 + r) * 1024 + h * 64 + cg * 8, qt + c * 8);
  }
  __syncthreads();

  f32x4 pacc[8];
#pragma unroll
  for (int nt = 0; nt < 8; ++nt) pacc[nt] = (f32x4){0.f, 0.f, 0.f, 0.f};
#pragma unroll
  for (int ks = 0; ks < 2; ++ks) {
    const int kb8 = (ks * 4 + lq) * 8;
    s8v af = *(s8v*)&qt[(w * 16 + l15) * 64 + (kb8 ^ sx)];
#pragma unroll
    for (int nt = 0; nt < 8; ++nt) pacc[nt] = MFMA_BF16(af, pf[nt][ks], pacc[nt]);
  }

  f32x4 aacc[4];
#pragma unroll
  for (int j = 0; j < 4; ++j) aacc[j] = (f32x4){0.f, 0.f, 0.f, 0.f};

#pragma unroll
  for (int half = 0; half < 2; ++half) {
    // q' half -> qA [64][136]
#pragma unroll
    for (int nt = 0; nt < 8; ++nt)
#pragma unroll
      for (int r = 0; r < 4; ++r) {
        float p = pacc[nt][r] * P_SCALE;
        float fv = (half == 0) ? __cosf(p) : __sinf(p);
        qA[(w * 16 + lq * 4 + r) * 136 + nt * 16 + l15] = (short)f2bf(fv * F_SCALE);
      }
    // stage kvT half: [64 d][128 m'], swizzled (16 chunks/row)
#pragma unroll
    for (int i = 0; i < 4; ++i) {
      int c = t + i * 256;                 // chunk 0..1023
      int d = c >> 4, cl = c & 15;
      int cg = cl ^ (d & 15);
      gload_lds16(kvT + (size_t)((b * 16 + h) * 64 + d) * 256 + half * 128 + cg * 8,
                  kvt + c * 8);
    }
    __syncthreads();
#pragma unroll
    for (int ks = 0; ks < 4; ++ks) {
      s8v af = *(s8v*)&qA[(w * 16 + l15) * 136 + ks * 32 + lq * 8];
#pragma unroll
      for (int j = 0; j < 4; ++j) {
        int row = j * 16 + l15;
        s8v bf4 = *(s8v*)&kvt[row * 128 + (((ks * 4 + lq) ^ l15) * 8)];
        aacc[j] = MFMA_BF16(af, bf4, aacc[j]);
      }
    }
    __syncthreads();
  }

  // epilogue image at smem base [64][72]
#pragma unroll
  for (int j = 0; j < 4; ++j)
#pragma unroll
    for (int r = 0; r < 4; ++r)
      smem[(w * 16 + lq * 4 + r) * 72 + j * 16 + l15] = (short)f2bf(aacc[j][r]);
  __syncthreads();
#pragma unroll
  for (int i = 0; i < 2; ++i) {
    int c = t + i * 256;
    int r = c >> 3, cc = c & 7;
    *(s8v*)&attnb[(size_t)(row0 + r) * 1024 + h * 64 + cc * 8] = *(s8v*)&smem[r * 72 + cc * 8];
  }
}

// ---------------------------------------------------------------------------
// K4: out = attn @ Wo^T + bo. fp32 out. grid (128, 8).
// ---------------------------------------------------------------------------
__global__ void out_gemm_kernel(const short* __restrict__ attnb, const short* __restrict__ Wob,
                                const float* __restrict__ bo_, float* __restrict__ out) {
  __shared__ __align__(16) short smem[16384];
  short* Al = smem;
  short* Bl = smem + 8192;

  const int t = threadIdx.x;
  const int bm = blockIdx.x, bn = blockIdx.y;
  const int row0 = bm * 128, n0 = bn * 128;
  const int lane = t & 63, w = t >> 6;
  const int wm = w & 1, wn = w >> 1;
  const int l15 = lane & 15, lq = lane >> 4;
  const int sx = (l15 & 7) * 8;

  f32x4 acc[4][4];
#pragma unroll
  for (int i = 0; i < 4; ++i)
#pragma unroll
    for (int j = 0; j < 4; ++j) acc[i][j] = (f32x4){0.f, 0.f, 0.f, 0.f};

  for (int k0 = 0; k0 < 1024; k0 += 64) {
#pragma unroll
    for (int i = 0; i < 4; ++i) {
      int c = t + i * 256;
      int r = c >> 3, cl = c & 7;
      int cg = cl ^ (r & 7);
      gload_lds16(attnb + (size_t)(row0 + r) * 1024 + k0 + cg * 8, Al + c * 8);
      gload_lds16(Wob   + (size_t)(n0 + r) * 1024 + k0 + cg * 8, Bl + c * 8);
    }
    __syncthreads();
#pragma unroll
    for (int ks = 0; ks < 2; ++ks) {
      const int kb8 = (ks * 4 + lq) * 8;
      s8v af[4], bfr[4];
#pragma unroll
      for (int i = 0; i < 4; ++i)
        af[i] = *(s8v*)&Al[(wm * 64 + i * 16 + l15) * 64 + (kb8 ^ sx)];
#pragma unroll
      for (int j = 0; j < 4; ++j)
        bfr[j] = *(s8v*)&Bl[(wn * 64 + j * 16 + l15) * 64 + (kb8 ^ sx)];
#pragma unroll
      for (int i = 0; i < 4; ++i)
#pragma unroll
        for (int j = 0; j < 4; ++j)
          acc[i][j] = MFMA_BF16(af[i], bfr[j], acc[i][j]);
    }
    __syncthreads();
  }

#pragma unroll
  for (int j = 0; j < 4; ++j) {
    int cl = wn * 64 + j * 16 + l15;
    float bsv = bo_[n0 + cl];
#pragma unroll
    for (int i = 0; i < 4; ++i)
#pragma unroll
      for (int r = 0; r < 4; ++r)
        out[(size_t)(row0 + wm * 64 + i * 16 + lq * 4 + r) * 1024 + n0 + cl] =
            acc[i][j][r] + bsv;
  }
}

// ---------------------------------------------------------------------------
extern "C" void kernel_launch(void* const* d_in, const int* in_sizes, int n_in,
                              void* d_out, int out_size, void* d_ws, size_t ws_size,
                              hipStream_t stream) {
  const float* x    = (const float*)d_in[0];
  const float* proj = (const float*)d_in[1];
  const float* Wq   = (const float*)d_in[2];
  const float* bq   = (const float*)d_in[3];
  const float* Wk   = (const float*)d_in[4];
  const float* bk   = (const float*)d_in[5];
  const float* Wv   = (const float*)d_in[6];
  const float* bv   = (const float*)d_in[7];
  const float* Wo   = (const float*)d_in[8];
  const float* bo   = (const float*)d_in[9];
  float* out = (float*)d_out;

  char* wsb = (char*)d_ws;
  short* qb    = (short*)(wsb + 0);
  short* kb    = (short*)(wsb + 33554432);
  short* vT    = (short*)(wsb + 67108864);
  short* xb    = (short*)(wsb + 100663296);
  short* Wqkvb = (short*)(wsb + 134217728);
  short* Wob   = (short*)(wsb + 140509184);
  short* projT = (short*)(wsb + 142606336);
  float* kv_part = (float*)(wsb + 100663296);  // 32MB, overlays xb (dead after K1)
  short* attnb = kb;                            // kb dead after K2
  short* kvT   = vT;                            // vT dead after K2

  conv_all_kernel<<<dim3(2048), dim3(256), 0, stream>>>(
      x, Wq, Wk, Wv, Wo, proj, xb, Wqkvb, Wob, projT);

  qkv_gemm_kernel<<<dim3(128, 24), dim3(256), 0, stream>>>(xb, Wqkvb, bq, bk, bv, qb, kb, vT);
  kv_accum_kernel<<<dim3(512), dim3(256), 0, stream>>>(kb, vT, projT, kv_part);
  kvT_kernel<<<dim3(64, 4), dim3(256), 0, stream>>>(kv_part, kvT);
  attn_kernel<<<dim3(256, 16), dim3(256), 0, stream>>>(qb, projT, kvT, attnb);
  out_gemm_kernel<<<dim3(128, 8), dim3(256), 0, stream>>>(attnb, Wob, bo, out);
}